// Round 12
// baseline (146.164 us; speedup 1.0000x reference)
//
#include <hip/hip_runtime.h>
#include <cmath>

// ---------------------------------------------------------------------------
// 2-layer GAT, N=10000, E=160000(+self loops in CSR), F_IN=256 ->
// [8x128 concat]=1024 -> ELU -> [1x64]. All GEMMs single-term fp16 MFMA
// (fp32 accum). agg1: XCD-sharded per-head gather (chunk = blockIdx%8 -> each
// XCD's L2 holds one 2.6MB head-slice of h1b), 2-deep prefetch, quad-split.
// ---------------------------------------------------------------------------

typedef _Float16 f16x8 __attribute__((ext_vector_type(8)));
typedef float f32x4 __attribute__((ext_vector_type(4)));
typedef unsigned short u16x8 __attribute__((ext_vector_type(8)));

__device__ __forceinline__ float lrelu(float x) { return x > 0.f ? x : 0.2f * x; }
__device__ __forceinline__ unsigned short f2h(float f) {
  _Float16 h = (_Float16)f;
  return __builtin_bit_cast(unsigned short, h);
}
__device__ __forceinline__ float h2f(unsigned short u) {
  return (float)__builtin_bit_cast(_Float16, u);
}

__device__ __forceinline__ void fma8h(float* acc, uint4 v, float e) {
  acc[0] += e * h2f((unsigned short)(v.x & 0xffffu));
  acc[1] += e * h2f((unsigned short)(v.x >> 16));
  acc[2] += e * h2f((unsigned short)(v.y & 0xffffu));
  acc[3] += e * h2f((unsigned short)(v.y >> 16));
  acc[4] += e * h2f((unsigned short)(v.z & 0xffffu));
  acc[5] += e * h2f((unsigned short)(v.z >> 16));
  acc[6] += e * h2f((unsigned short)(v.w & 0xffffu));
  acc[7] += e * h2f((unsigned short)(v.w >> 16));
}

#define GLOAD_LDS16(gsrc, ldst)                                              \
  __builtin_amdgcn_global_load_lds(                                          \
      (const __attribute__((address_space(1))) unsigned int*)(gsrc),         \
      (__attribute__((address_space(3))) unsigned int*)(ldst), 16, 0, 0)

// ---- fused prep: count (atomics) + pack_x + pack_w1 + pack_w2 (all fp16) --
// Subtile = 16(rows) x 32(k) fp16 = 1024B, lane-linear: lane l supplies
// (row = l&15, kchunk = l>>4), 16B per lane.

__global__ __launch_bounds__(256) void prep_fused(
    const int* __restrict__ ei, int* __restrict__ counts, int E,
    const float* __restrict__ x, unsigned short* __restrict__ xpk, int N, int MB1,
    const float* __restrict__ W1, unsigned short* __restrict__ w1pk,
    const float* __restrict__ W2, unsigned short* __restrict__ w2pk) {
  const int countB = (E + 255) / 256;
  const int pxB = MB1 * 8;
  int bid = blockIdx.x;
  int t = threadIdx.x;

  if (bid < countB) {  // ---- degree count
    int e = bid * 256 + t;
    if (e < E) atomicAdd(&counts[ei[E + e]], 1);
    return;
  }
  bid -= countB;
  if (bid < pxB) {  // ---- pack x (fp16, zero-padded rows)
    int mb = bid >> 3, ks = bid & 7;
    int l = t & 63, f = t >> 6;
    int row = mb * 64 + f * 16 + (l & 15);
    int kc = ks * 32 + (l >> 4) * 8;
    float v[8];
#pragma unroll
    for (int j = 0; j < 8; ++j) v[j] = 0.f;
    if (row < N) {
      const float* xr = x + (size_t)row * 256 + kc;
#pragma unroll
      for (int j = 0; j < 8; ++j) v[j] = xr[j];
    }
    u16x8 hv;
#pragma unroll
    for (int j = 0; j < 8; ++j) hv[j] = f2h(v[j]);
    size_t base = (size_t)(mb * 8 + ks) * 2048;
    *(u16x8*)(xpk + base + (size_t)f * 512 + l * 8) = hv;
    return;
  }
  bid -= pxB;
  if (bid < 64) {  // ---- pack W1^T (fp16)
    int hb = bid >> 3, ks = bid & 7;
    int l = t & 63, gq = t >> 6;
    for (int g = gq; g < 8; g += 4) {
      int n = hb * 128 + g * 16 + (l & 15);
      int k0 = ks * 32 + (l >> 4) * 8;
      u16x8 hv;
#pragma unroll
      for (int j = 0; j < 8; ++j) hv[j] = f2h(W1[(size_t)(k0 + j) * 1024 + n]);
      size_t base = (size_t)(hb * 8 + ks) * 4096;
      *(u16x8*)(w1pk + base + (size_t)g * 512 + l * 8) = hv;
    }
    return;
  }
  bid -= 64;
  {  // ---- pack W2^T (fp16, 32 blocks)
    int ks = bid;
    int l = t & 63, g = t >> 6;
    int n = g * 16 + (l & 15);
    int k0 = ks * 32 + (l >> 4) * 8;
    u16x8 hv;
#pragma unroll
    for (int j = 0; j < 8; ++j) hv[j] = f2h(W2[(size_t)(k0 + j) * 64 + n]);
    size_t base = (size_t)ks * 2048;
    *(u16x8*)(w2pk + base + (size_t)g * 512 + l * 8) = hv;
  }
}

// ---- CSR scan (v[i] = counts[i] + 1 for self loop) ------------------------

__global__ __launch_bounds__(256) void scan_blk(const int* __restrict__ counts,
                                                int* __restrict__ offsets,
                                                int* __restrict__ bsum, int n) {
  __shared__ int lds[256];
  int b = blockIdx.x, t = threadIdx.x, i = b * 256 + t;
  int v = (i < n) ? counts[i] + 1 : 0;
  lds[t] = v;
  __syncthreads();
  for (int off = 1; off < 256; off <<= 1) {
    int tv = (t >= off) ? lds[t - off] : 0;
    __syncthreads();
    lds[t] += tv;
    __syncthreads();
  }
  if (i < n) offsets[i] = lds[t] - v;
  if (t == 255) bsum[b] = lds[255];
}

__global__ __launch_bounds__(256) void scan_apply(int* __restrict__ offsets,
                                                  int* __restrict__ cursors,
                                                  const int* __restrict__ bsum,
                                                  int nb, int n) {
  __shared__ int pre_s;
  int b = blockIdx.x, t = threadIdx.x;
  if (t == 0) {
    int s = 0;
    for (int i = 0; i < b; ++i) s += bsum[i];
    pre_s = s;
    if (b == nb - 1) {
      int tot = s;
      for (int i = b; i < nb; ++i) tot += bsum[i];
      offsets[n] = tot;
    }
  }
  __syncthreads();
  int i = b * 256 + t;
  if (i < n) {
    int o = offsets[i] + pre_s;
    offsets[i] = o;
    cursors[i] = o;
  }
}

__global__ __launch_bounds__(256) void fill_all(const int* __restrict__ ei,
                                                int* __restrict__ cursors,
                                                const int* __restrict__ offsets,
                                                int* __restrict__ list,
                                                int E, int n) {
  int tid = blockIdx.x * 256 + threadIdx.x;
  if (tid < E) {
    int d = ei[E + tid];
    int pos = atomicAdd(&cursors[d], 1);
    list[pos] = ei[tid];
  } else if (tid < E + n) {
    int i = tid - E;
    list[offsets[i + 1] - 1] = i;  // self loop in last slot
  }
}

// ---- GEMM1 (fp16 MFMA) + fused att1 dots ----------------------------------
// BM=128, BN=128 (one head), BK=32, 512 thr (8 waves: 2 row x 4 col).
// LDS per buf 16KB: [A 8K][B 8K]; dbuf = 32KB; epilogue needs 36.9KB.

__global__ __launch_bounds__(512, 4) void gemm1_att(
    const unsigned short* __restrict__ xpk, const unsigned short* __restrict__ w1pk,
    const float* __restrict__ asrc, const float* __restrict__ adst,
    unsigned short* __restrict__ h1b, float* __restrict__ as1,
    float* __restrict__ ad1) {
  extern __shared__ char sm[];
  const int t = threadIdx.x, wid = t >> 6, lane = t & 63;
  const int wr = wid >> 2, wc = wid & 3;
  const int mb = blockIdx.x, hb = blockIdx.y;
  const int m0 = mb * 128;
  const int l15 = lane & 15, l4 = lane >> 4;

  f32x4 acc[4][2] = {};

  auto stage = [&](int buf, int ks) {
    char* base0 = sm + buf * 16384;
    for (int i = wid; i < 16; i += 8) {
      const unsigned short* src;
      int ldsoff;
      if (i < 8) {  // A subtile: pack-block r=i>>2, f=i&3
        int r = i >> 2;
        src = xpk + (size_t)((2 * mb + r) * 8 + ks) * 2048 + (i & 3) * 512 + lane * 8;
        ldsoff = i * 1024;
      } else {  // B subtile g=i-8
        int g = i - 8;
        src = w1pk + (size_t)(hb * 8 + ks) * 4096 + g * 512 + lane * 8;
        ldsoff = 8192 + g * 1024;
      }
      GLOAD_LDS16(src, base0 + ldsoff);
    }
  };

  stage(0, 0);
  __syncthreads();
  int buf = 0;
  for (int step = 0; step < 8; ++step) {
    if (step < 7) stage(buf ^ 1, step + 1);
    const char* b = sm + buf * 16384;
    f16x8 ah[4], bh[2];
#pragma unroll
    for (int mf = 0; mf < 4; ++mf)
      ah[mf] = *(const f16x8*)(b + (wr * 4 + mf) * 1024 + lane * 16);
#pragma unroll
    for (int nf = 0; nf < 2; ++nf)
      bh[nf] = *(const f16x8*)(b + 8192 + (wc * 2 + nf) * 1024 + lane * 16);
#pragma unroll
    for (int mf = 0; mf < 4; ++mf)
#pragma unroll
      for (int nf = 0; nf < 2; ++nf)
        acc[mf][nf] = __builtin_amdgcn_mfma_f32_16x16x32_f16(ah[mf], bh[nf], acc[mf][nf], 0, 0, 0);
    __syncthreads();
    buf ^= 1;
  }

  // epilogue: fused att dots + fp16 C-tile via LDS (coalesced out)
  float* parts_s = (float*)sm;                           // [128][4]
  float* parts_d = (float*)(sm + 2048);                  // [128][4]
  unsigned short* ctile = (unsigned short*)(sm + 4096);  // [128][128]
  float as_c[2], ad_c[2];
#pragma unroll
  for (int nf = 0; nf < 2; ++nf) {
    int col = hb * 128 + wc * 32 + nf * 16 + l15;
    as_c[nf] = asrc[col];
    ad_c[nf] = adst[col];
  }
#pragma unroll
  for (int mf = 0; mf < 4; ++mf) {
    float ss[4] = {0.f, 0.f, 0.f, 0.f}, dd[4] = {0.f, 0.f, 0.f, 0.f};
#pragma unroll
    for (int nf = 0; nf < 2; ++nf)
#pragma unroll
      for (int r = 0; r < 4; ++r) {
        ss[r] += acc[mf][nf][r] * as_c[nf];
        dd[r] += acc[mf][nf][r] * ad_c[nf];
      }
#pragma unroll
    for (int r = 0; r < 4; ++r)
      for (int m = 1; m < 16; m <<= 1) {
        ss[r] += __shfl_xor(ss[r], m);
        dd[r] += __shfl_xor(dd[r], m);
      }
    if (l15 == 0) {
#pragma unroll
      for (int r = 0; r < 4; ++r) {
        int row = wr * 64 + mf * 16 + l4 * 4 + r;
        parts_s[row * 4 + wc] = ss[r];
        parts_d[row * 4 + wc] = dd[r];
      }
    }
#pragma unroll
    for (int nf = 0; nf < 2; ++nf)
#pragma unroll
      for (int r = 0; r < 4; ++r) {
        int row = wr * 64 + mf * 16 + l4 * 4 + r;
        int col = wc * 32 + nf * 16 + l15;
        ctile[row * 128 + col] = f2h(acc[mf][nf][r]);
      }
  }
  __syncthreads();
  if (t < 128) {
    float s = parts_s[t * 4] + parts_s[t * 4 + 1] + parts_s[t * 4 + 2] + parts_s[t * 4 + 3];
    float d = parts_d[t * 4] + parts_d[t * 4 + 1] + parts_d[t * 4 + 2] + parts_d[t * 4 + 3];
    as1[(size_t)(m0 + t) * 8 + hb] = s;
    ad1[(size_t)(m0 + t) * 8 + hb] = d;
  }
#pragma unroll
  for (int rep = 0; rep < 4; ++rep) {
    int e = rep * 4096 + t * 8;
    int row = e >> 7, col = e & 127;
    u16x8 v = *(const u16x8*)(ctile + e);
    *(u16x8*)(h1b + (size_t)(m0 + row) * 1024 + hb * 128 + col) = v;
  }
}

// ---- layer-1 gather: XCD-sharded per-head, 2-deep prefetch, quad-split ----
// Work item = (node-quad q, head c); c = item&7 is constant per block when
// gridDim%8==0, so all blocks touching head c land on one XCD whose L2 then
// holds h1b's 2.6MB head-c slice. Wave = 1 node; 4 edge-quads of 16 lanes;
// lane owns 8 channels (16B) of the 128-ch head row.

__global__ __launch_bounds__(256) void agg1_gather(
    const unsigned short* __restrict__ h1b, const float* __restrict__ as1,
    const float* __restrict__ ad1, const int* __restrict__ offsets,
    const int* __restrict__ list, const float* __restrict__ b1,
    unsigned short* __restrict__ o1pk, int n, int nitems) {
  const int w = threadIdx.x >> 6, lane = threadIdx.x & 63;
  const int quad = lane >> 4, li = lane & 15;

  for (int item = blockIdx.x; item < nitems; item += gridDim.x) {
    const int c = item & 7;   // head / channel chunk
    const int q = item >> 3;  // node quad
    const int node = q * 4 + w;
    if (node >= n) continue;
    const int beg = offsets[node], end = offsets[node + 1];
    const float adc = ad1[(size_t)node * 8 + c];
    const unsigned short* hrow = h1b + (size_t)c * 128 + (size_t)li * 8;

    float acc[8] = {};
    float den = 0.f;
    int j = beg + quad;
    int s0 = 0;
    float a0 = 0.f;
    uint4 v0 = make_uint4(0, 0, 0, 0);
    if (j < end) {
      s0 = list[j];
      a0 = as1[(size_t)s0 * 8 + c];
      v0 = *(const uint4*)(hrow + (size_t)s0 * 1024);
    }
    for (; j + 4 < end; j += 4) {
      int s1 = list[j + 4];
      float a1 = as1[(size_t)s1 * 8 + c];
      uint4 v1 = *(const uint4*)(hrow + (size_t)s1 * 1024);
      float e = __expf(lrelu(a0 + adc));
      den += e;
      fma8h(acc, v0, e);
      s0 = s1; a0 = a1; v0 = v1;
    }
    if (j < end) {
      float e = __expf(lrelu(a0 + adc));
      den += e;
      fma8h(acc, v0, e);
    }
    // cross-quad reduce (quads handled disjoint edges of the same node)
#pragma unroll
    for (int k = 0; k < 8; ++k) {
      acc[k] += __shfl_xor(acc[k], 16);
      acc[k] += __shfl_xor(acc[k], 32);
    }
    den += __shfl_xor(den, 16);
    den += __shfl_xor(den, 32);
    if (quad == 0) {
      float inv = 1.f / (den + 1e-16f);
      u16x8 hv;
#pragma unroll
      for (int k = 0; k < 8; ++k) {
        float v = acc[k] * inv + b1[c * 128 + li * 8 + k];
        v = v > 0.f ? v : expm1f(v);
        hv[k] = f2h(v);
      }
      // packed o1pk write (same formula as gemm2's A-read layout)
      int mb = node >> 6, f = (node >> 4) & 3, l15n = node & 15;
      int ks = 4 * c + (li >> 2), kc = li & 3;
      size_t g = (size_t)(mb * 32 + ks) * 2048 + (size_t)f * 512 +
                 (size_t)(kc * 16 + l15n) * 8;
      *(u16x8*)(o1pk + g) = hv;
    }
  }
}

// ---- GEMM2 (fp16 MFMA, split-K=4) -----------------------------------------
// BM=64, BN=64, BK=32, 8 K-steps per block. LDS/buf 8KB: [A 4K][B 4K].

__global__ __launch_bounds__(256) void gemm2_splitk(
    const unsigned short* __restrict__ o1pk, const unsigned short* __restrict__ w2pk,
    float* __restrict__ h2p, int Mpad) {
  extern __shared__ char sm[];
  const int t = threadIdx.x, wid = t >> 6, lane = t & 63;
  const int wr = wid >> 1, wc = wid & 1;
  const int mb = blockIdx.x, sk = blockIdx.y;
  const int m0 = mb * 64;
  const int l15 = lane & 15, l4 = lane >> 4;

  f32x4 acc[2][2] = {};

  auto stage = [&](int buf, int ks) {
    char* base0 = sm + buf * 8192;
    const unsigned short* ax = o1pk + (size_t)(mb * 32 + ks) * 2048 + lane * 8;
    const unsigned short* bw = w2pk + (size_t)ks * 2048 + lane * 8;
    GLOAD_LDS16(ax + wid * 512, base0 + wid * 1024);
    GLOAD_LDS16(bw + wid * 512, base0 + 4096 + wid * 1024);
  };

  stage(0, sk * 8);
  __syncthreads();
  int buf = 0;
  for (int step = 0; step < 8; ++step) {
    if (step < 7) stage(buf ^ 1, sk * 8 + step + 1);
    const char* b = sm + buf * 8192;
    f16x8 ah[2], bh[2];
#pragma unroll
    for (int mf = 0; mf < 2; ++mf)
      ah[mf] = *(const f16x8*)(b + (wr * 2 + mf) * 1024 + lane * 16);
#pragma unroll
    for (int nf = 0; nf < 2; ++nf)
      bh[nf] = *(const f16x8*)(b + 4096 + (wc * 2 + nf) * 1024 + lane * 16);
#pragma unroll
    for (int mf = 0; mf < 2; ++mf)
#pragma unroll
      for (int nf = 0; nf < 2; ++nf)
        acc[mf][nf] = __builtin_amdgcn_mfma_f32_16x16x32_f16(ah[mf], bh[nf], acc[mf][nf], 0, 0, 0);
    __syncthreads();
    buf ^= 1;
  }

#pragma unroll
  for (int mf = 0; mf < 2; ++mf)
#pragma unroll
    for (int nf = 0; nf < 2; ++nf)
#pragma unroll
      for (int r = 0; r < 4; ++r) {
        int row = wr * 32 + mf * 16 + l4 * 4 + r;
        int col = wc * 32 + nf * 16 + l15;
        h2p[((size_t)sk * Mpad + m0 + row) * 64 + col] = acc[mf][nf][r];
      }
}

// ---- reduce split-K partials + att2 dots ----------------------------------

__global__ __launch_bounds__(256) void reduce_att2(
    const float* __restrict__ h2p, const float* __restrict__ asrc,
    const float* __restrict__ adst, float* __restrict__ h2,
    float* __restrict__ as2, float* __restrict__ ad2, int Mpad, int n) {
  int w = threadIdx.x >> 6, lane = threadIdx.x & 63;
  int row = blockIdx.x * 4 + w;
  if (row >= n) return;
  float s = 0.f;
#pragma unroll
  for (int sk = 0; sk < 4; ++sk) s += h2p[((size_t)sk * Mpad + row) * 64 + lane];
  h2[(size_t)row * 64 + lane] = s;
  float ds = s * asrc[lane], dd = s * adst[lane];
  for (int o = 32; o; o >>= 1) { ds += __shfl_xor(ds, o); dd += __shfl_xor(dd, o); }
  if (lane == 0) { as2[row] = ds; ad2[row] = dd; }
}

// ---- layer-2 gather: one wave per node, grid-stride -----------------------

__global__ __launch_bounds__(256) void agg2_gather(
    const float* __restrict__ h2, const float* __restrict__ as2,
    const float* __restrict__ ad2, const int* __restrict__ offsets,
    const int* __restrict__ list, const float* __restrict__ b2,
    float* __restrict__ out, int n, int nblk) {
  const int wid = threadIdx.x >> 6, lane = threadIdx.x & 63;
  const int cb = (lane & 15) * 4;  // 4 channels per lane
  const int jo = lane >> 4;        // row-in-quad

  for (int blk = blockIdx.x; blk < nblk; blk += gridDim.x) {
    const int node = blk * 4 + wid;
    if (node >= n) continue;
    const int beg = offsets[node], end = offsets[node + 1];
    const float ad = ad2[node];

    float4 acc = make_float4(0.f, 0.f, 0.f, 0.f);
    float den = 0.f;
    for (int j = beg + jo; j < end; j += 4) {
      int s = list[j];
      float e = __expf(lrelu(as2[s] + ad));
      den += e;
      float4 v = *(const float4*)&h2[(size_t)s * 64 + cb];
      acc.x += e * v.x; acc.y += e * v.y; acc.z += e * v.z; acc.w += e * v.w;
    }
    acc.x += __shfl_xor(acc.x, 16); acc.y += __shfl_xor(acc.y, 16);
    acc.z += __shfl_xor(acc.z, 16); acc.w += __shfl_xor(acc.w, 16);
    den += __shfl_xor(den, 16);
    acc.x += __shfl_xor(acc.x, 32); acc.y += __shfl_xor(acc.y, 32);
    acc.z += __shfl_xor(acc.z, 32); acc.w += __shfl_xor(acc.w, 32);
    den += __shfl_xor(den, 32);
    if (jo == 0) {
      float inv = 1.f / (den + 1e-16f);
      float4 r;
      r.x = acc.x * inv + b2[cb];
      r.y = acc.y * inv + b2[cb + 1];
      r.z = acc.z * inv + b2[cb + 2];
      r.w = acc.w * inv + b2[cb + 3];
      *(float4*)&out[(size_t)node * 64 + cb] = r;
    }
  }
}

// ---------------------------------------------------------------------------

extern "C" void kernel_launch(void* const* d_in, const int* in_sizes, int n_in,
                              void* d_out, int out_size, void* d_ws, size_t ws_size,
                              hipStream_t stream) {
  const float* x     = (const float*)d_in[0];
  const int*   ei    = (const int*)d_in[1];
  const float* W1    = (const float*)d_in[2];
  const float* asrc1 = (const float*)d_in[3];
  const float* adst1 = (const float*)d_in[4];
  const float* b1    = (const float*)d_in[5];
  const float* W2    = (const float*)d_in[6];
  const float* asrc2 = (const float*)d_in[7];
  const float* adst2 = (const float*)d_in[8];
  const float* b2    = (const float*)d_in[9];
  float* out = (float*)d_out;

  const int N = in_sizes[0] / 256;
  const int E = in_sizes[1] / 2;
  const int T = E + N;  // edges + self loops
  const int MBB = (N + 127) / 128;  // gemm1 M-blocks
  const int Mpad = MBB * 128;
  const int MB1 = Mpad / 64;        // 64-row pack blocks
  const int NB = (N + 255) / 256;
  const int NBLK4 = (N + 3) / 4;
  const int NITEMS1 = NBLK4 * 8;    // (node-quad, head) work items
  const int AGG1_GRID = NITEMS1 < 2048 ? NITEMS1 : 2048;  // multiple of 8
  const int AGG2_GRID = NBLK4 < 2048 ? NBLK4 : 2048;

  char* p = (char*)d_ws;
  auto bump = [&](size_t bytes) {
    char* r = p;
    p += (bytes + 255) & ~(size_t)255;
    return r;
  };
  int* counts  = (int*)bump((size_t)N * 4);
  int* offsets = (int*)bump((size_t)(N + 1) * 4);
  int* cursors = (int*)bump((size_t)N * 4);
  int* bsum    = (int*)bump((size_t)NB * 4);
  int* list    = (int*)bump((size_t)T * 4);
  unsigned short* xpk  = (unsigned short*)bump((size_t)Mpad * 256 * 2);   // fp16
  unsigned short* w1pk = (unsigned short*)bump((size_t)1024 * 256 * 2);
  unsigned short* h1b  = (unsigned short*)bump((size_t)Mpad * 1024 * 2);  // fp16
  float* as1           = (float*)bump((size_t)Mpad * 8 * 4);
  float* ad1           = (float*)bump((size_t)Mpad * 8 * 4);
  unsigned short* o1pk = (unsigned short*)bump((size_t)Mpad * 1024 * 2);  // fp16
  unsigned short* w2pk = (unsigned short*)bump((size_t)64 * 1024 * 2);
  float* as2           = (float*)bump((size_t)Mpad * 4);
  float* ad2           = (float*)bump((size_t)Mpad * 4);
  // aliases (safe: single-stream ordering; last reader precedes first writer)
  float* h2p = (float*)h1b;   // 4*Mpad*64*4B = Mpad*1KB <= Mpad*2KB
  float* h2  = (float*)xpk;   // Mpad*64*4B = Mpad*256B <= Mpad*512B

  // CSR + packing
  hipMemsetAsync(counts, 0, (size_t)N * 4, stream);
  {
    int gridsz = (E + 255) / 256 + MB1 * 8 + 64 + 32;
    prep_fused<<<gridsz, 256, 0, stream>>>(ei, counts, E, x, xpk, N, MB1,
                                           W1, w1pk, W2, w2pk);
  }
  scan_blk<<<NB, 256, 0, stream>>>(counts, offsets, bsum, N);
  scan_apply<<<NB, 256, 0, stream>>>(offsets, cursors, bsum, NB, N);
  fill_all<<<(E + N + 255) / 256, 256, 0, stream>>>(ei, cursors, offsets, list, E, N);

  // layer 1
  gemm1_att<<<dim3(MBB, 8), 512, 36864, stream>>>(xpk, w1pk, asrc1, adst1, h1b, as1, ad1);
  agg1_gather<<<AGG1_GRID, 256, 0, stream>>>(h1b, as1, ad1, offsets, list, b1, o1pk, N, NITEMS1);

  // layer 2
  gemm2_splitk<<<dim3(Mpad / 64, 4), 256, 16384, stream>>>(o1pk, w2pk, h2p, Mpad);
  reduce_att2<<<(N + 3) / 4, 256, 0, stream>>>(h2p, asrc2, adst2, h2, as2, ad2, Mpad, N);
  agg2_gather<<<AGG2_GRID, 256, 0, stream>>>(h2, as2, ad2, offsets, list, b2, out, N, NBLK4);
}

// Round 13
// 131.601 us; speedup vs baseline: 1.1107x; 1.1107x over previous
//
#include <hip/hip_runtime.h>
#include <cmath>

// ---------------------------------------------------------------------------
// 2-layer GAT, N=10000, E=160000(+self loops in CSR), F_IN=256 ->
// [8x128 concat]=1024 -> ELU -> [1x64]. All GEMMs single-term fp16 MFMA
// (fp32 accum). agg1: XCD-sharded per-head gather (chunk = blockIdx%8 -> each
// XCD's L2 holds one 2.6MB head-slice of h1b), cheap-ELU all-lane epilogue.
// ---------------------------------------------------------------------------

typedef _Float16 f16x8 __attribute__((ext_vector_type(8)));
typedef float f32x4 __attribute__((ext_vector_type(4)));
typedef unsigned short u16x8 __attribute__((ext_vector_type(8)));

__device__ __forceinline__ float lrelu(float x) { return x > 0.f ? x : 0.2f * x; }
__device__ __forceinline__ unsigned short f2h(float f) {
  _Float16 h = (_Float16)f;
  return __builtin_bit_cast(unsigned short, h);
}
__device__ __forceinline__ float h2f(unsigned short u) {
  return (float)__builtin_bit_cast(_Float16, u);
}

__device__ __forceinline__ void fma8h(float* acc, uint4 v, float e) {
  acc[0] += e * h2f((unsigned short)(v.x & 0xffffu));
  acc[1] += e * h2f((unsigned short)(v.x >> 16));
  acc[2] += e * h2f((unsigned short)(v.y & 0xffffu));
  acc[3] += e * h2f((unsigned short)(v.y >> 16));
  acc[4] += e * h2f((unsigned short)(v.z & 0xffffu));
  acc[5] += e * h2f((unsigned short)(v.z >> 16));
  acc[6] += e * h2f((unsigned short)(v.w & 0xffffu));
  acc[7] += e * h2f((unsigned short)(v.w >> 16));
}

#define GLOAD_LDS16(gsrc, ldst)                                              \
  __builtin_amdgcn_global_load_lds(                                          \
      (const __attribute__((address_space(1))) unsigned int*)(gsrc),         \
      (__attribute__((address_space(3))) unsigned int*)(ldst), 16, 0, 0)

// ---- fused prep: count (atomics) + pack_x + pack_w1 + pack_w2 (all fp16) --
// Subtile = 16(rows) x 32(k) fp16 = 1024B, lane-linear: lane l supplies
// (row = l&15, kchunk = l>>4), 16B per lane.

__global__ __launch_bounds__(256) void prep_fused(
    const int* __restrict__ ei, int* __restrict__ counts, int E,
    const float* __restrict__ x, unsigned short* __restrict__ xpk, int N, int MB1,
    const float* __restrict__ W1, unsigned short* __restrict__ w1pk,
    const float* __restrict__ W2, unsigned short* __restrict__ w2pk) {
  const int countB = (E + 255) / 256;
  const int pxB = MB1 * 8;
  int bid = blockIdx.x;
  int t = threadIdx.x;

  if (bid < countB) {  // ---- degree count
    int e = bid * 256 + t;
    if (e < E) atomicAdd(&counts[ei[E + e]], 1);
    return;
  }
  bid -= countB;
  if (bid < pxB) {  // ---- pack x (fp16, zero-padded rows)
    int mb = bid >> 3, ks = bid & 7;
    int l = t & 63, f = t >> 6;
    int row = mb * 64 + f * 16 + (l & 15);
    int kc = ks * 32 + (l >> 4) * 8;
    float v[8];
#pragma unroll
    for (int j = 0; j < 8; ++j) v[j] = 0.f;
    if (row < N) {
      const float* xr = x + (size_t)row * 256 + kc;
#pragma unroll
      for (int j = 0; j < 8; ++j) v[j] = xr[j];
    }
    u16x8 hv;
#pragma unroll
    for (int j = 0; j < 8; ++j) hv[j] = f2h(v[j]);
    size_t base = (size_t)(mb * 8 + ks) * 2048;
    *(u16x8*)(xpk + base + (size_t)f * 512 + l * 8) = hv;
    return;
  }
  bid -= pxB;
  if (bid < 64) {  // ---- pack W1^T (fp16)
    int hb = bid >> 3, ks = bid & 7;
    int l = t & 63, gq = t >> 6;
    for (int g = gq; g < 8; g += 4) {
      int n = hb * 128 + g * 16 + (l & 15);
      int k0 = ks * 32 + (l >> 4) * 8;
      u16x8 hv;
#pragma unroll
      for (int j = 0; j < 8; ++j) hv[j] = f2h(W1[(size_t)(k0 + j) * 1024 + n]);
      size_t base = (size_t)(hb * 8 + ks) * 4096;
      *(u16x8*)(w1pk + base + (size_t)g * 512 + l * 8) = hv;
    }
    return;
  }
  bid -= 64;
  {  // ---- pack W2^T (fp16, 32 blocks)
    int ks = bid;
    int l = t & 63, g = t >> 6;
    int n = g * 16 + (l & 15);
    int k0 = ks * 32 + (l >> 4) * 8;
    u16x8 hv;
#pragma unroll
    for (int j = 0; j < 8; ++j) hv[j] = f2h(W2[(size_t)(k0 + j) * 64 + n]);
    size_t base = (size_t)ks * 2048;
    *(u16x8*)(w2pk + base + (size_t)g * 512 + l * 8) = hv;
  }
}

// ---- CSR scan (v[i] = counts[i] + 1 for self loop) ------------------------

__global__ __launch_bounds__(256) void scan_blk(const int* __restrict__ counts,
                                                int* __restrict__ offsets,
                                                int* __restrict__ bsum, int n) {
  __shared__ int lds[256];
  int b = blockIdx.x, t = threadIdx.x, i = b * 256 + t;
  int v = (i < n) ? counts[i] + 1 : 0;
  lds[t] = v;
  __syncthreads();
  for (int off = 1; off < 256; off <<= 1) {
    int tv = (t >= off) ? lds[t - off] : 0;
    __syncthreads();
    lds[t] += tv;
    __syncthreads();
  }
  if (i < n) offsets[i] = lds[t] - v;
  if (t == 255) bsum[b] = lds[255];
}

__global__ __launch_bounds__(256) void scan_apply(int* __restrict__ offsets,
                                                  int* __restrict__ cursors,
                                                  const int* __restrict__ bsum,
                                                  int nb, int n) {
  __shared__ int pre_s;
  int b = blockIdx.x, t = threadIdx.x;
  if (t == 0) {
    int s = 0;
    for (int i = 0; i < b; ++i) s += bsum[i];
    pre_s = s;
    if (b == nb - 1) {
      int tot = s;
      for (int i = b; i < nb; ++i) tot += bsum[i];
      offsets[n] = tot;
    }
  }
  __syncthreads();
  int i = b * 256 + t;
  if (i < n) {
    int o = offsets[i] + pre_s;
    offsets[i] = o;
    cursors[i] = o;
  }
}

__global__ __launch_bounds__(256) void fill_all(const int* __restrict__ ei,
                                                int* __restrict__ cursors,
                                                const int* __restrict__ offsets,
                                                int* __restrict__ list,
                                                int E, int n) {
  int tid = blockIdx.x * 256 + threadIdx.x;
  if (tid < E) {
    int d = ei[E + tid];
    int pos = atomicAdd(&cursors[d], 1);
    list[pos] = ei[tid];
  } else if (tid < E + n) {
    int i = tid - E;
    list[offsets[i + 1] - 1] = i;  // self loop in last slot
  }
}

// ---- GEMM1 (fp16 MFMA) + fused att1 dots ----------------------------------
// BM=128, BN=128 (one head), BK=32, 512 thr (8 waves: 2 row x 4 col).
// LDS per buf 16KB: [A 8K][B 8K]; dbuf = 32KB; epilogue needs 36.9KB.

__global__ __launch_bounds__(512, 4) void gemm1_att(
    const unsigned short* __restrict__ xpk, const unsigned short* __restrict__ w1pk,
    const float* __restrict__ asrc, const float* __restrict__ adst,
    unsigned short* __restrict__ h1b, float* __restrict__ as1,
    float* __restrict__ ad1) {
  extern __shared__ char sm[];
  const int t = threadIdx.x, wid = t >> 6, lane = t & 63;
  const int wr = wid >> 2, wc = wid & 3;
  const int mb = blockIdx.x, hb = blockIdx.y;
  const int m0 = mb * 128;
  const int l15 = lane & 15, l4 = lane >> 4;

  f32x4 acc[4][2] = {};

  auto stage = [&](int buf, int ks) {
    char* base0 = sm + buf * 16384;
    for (int i = wid; i < 16; i += 8) {
      const unsigned short* src;
      int ldsoff;
      if (i < 8) {  // A subtile: pack-block r=i>>2, f=i&3
        int r = i >> 2;
        src = xpk + (size_t)((2 * mb + r) * 8 + ks) * 2048 + (i & 3) * 512 + lane * 8;
        ldsoff = i * 1024;
      } else {  // B subtile g=i-8
        int g = i - 8;
        src = w1pk + (size_t)(hb * 8 + ks) * 4096 + g * 512 + lane * 8;
        ldsoff = 8192 + g * 1024;
      }
      GLOAD_LDS16(src, base0 + ldsoff);
    }
  };

  stage(0, 0);
  __syncthreads();
  int buf = 0;
  for (int step = 0; step < 8; ++step) {
    if (step < 7) stage(buf ^ 1, step + 1);
    const char* b = sm + buf * 16384;
    f16x8 ah[4], bh[2];
#pragma unroll
    for (int mf = 0; mf < 4; ++mf)
      ah[mf] = *(const f16x8*)(b + (wr * 4 + mf) * 1024 + lane * 16);
#pragma unroll
    for (int nf = 0; nf < 2; ++nf)
      bh[nf] = *(const f16x8*)(b + 8192 + (wc * 2 + nf) * 1024 + lane * 16);
#pragma unroll
    for (int mf = 0; mf < 4; ++mf)
#pragma unroll
      for (int nf = 0; nf < 2; ++nf)
        acc[mf][nf] = __builtin_amdgcn_mfma_f32_16x16x32_f16(ah[mf], bh[nf], acc[mf][nf], 0, 0, 0);
    __syncthreads();
    buf ^= 1;
  }

  // epilogue: fused att dots + fp16 C-tile via LDS (coalesced out)
  float* parts_s = (float*)sm;                           // [128][4]
  float* parts_d = (float*)(sm + 2048);                  // [128][4]
  unsigned short* ctile = (unsigned short*)(sm + 4096);  // [128][128]
  float as_c[2], ad_c[2];
#pragma unroll
  for (int nf = 0; nf < 2; ++nf) {
    int col = hb * 128 + wc * 32 + nf * 16 + l15;
    as_c[nf] = asrc[col];
    ad_c[nf] = adst[col];
  }
#pragma unroll
  for (int mf = 0; mf < 4; ++mf) {
    float ss[4] = {0.f, 0.f, 0.f, 0.f}, dd[4] = {0.f, 0.f, 0.f, 0.f};
#pragma unroll
    for (int nf = 0; nf < 2; ++nf)
#pragma unroll
      for (int r = 0; r < 4; ++r) {
        ss[r] += acc[mf][nf][r] * as_c[nf];
        dd[r] += acc[mf][nf][r] * ad_c[nf];
      }
#pragma unroll
    for (int r = 0; r < 4; ++r)
      for (int m = 1; m < 16; m <<= 1) {
        ss[r] += __shfl_xor(ss[r], m);
        dd[r] += __shfl_xor(dd[r], m);
      }
    if (l15 == 0) {
#pragma unroll
      for (int r = 0; r < 4; ++r) {
        int row = wr * 64 + mf * 16 + l4 * 4 + r;
        parts_s[row * 4 + wc] = ss[r];
        parts_d[row * 4 + wc] = dd[r];
      }
    }
#pragma unroll
    for (int nf = 0; nf < 2; ++nf)
#pragma unroll
      for (int r = 0; r < 4; ++r) {
        int row = wr * 64 + mf * 16 + l4 * 4 + r;
        int col = wc * 32 + nf * 16 + l15;
        ctile[row * 128 + col] = f2h(acc[mf][nf][r]);
      }
  }
  __syncthreads();
  if (t < 128) {
    float s = parts_s[t * 4] + parts_s[t * 4 + 1] + parts_s[t * 4 + 2] + parts_s[t * 4 + 3];
    float d = parts_d[t * 4] + parts_d[t * 4 + 1] + parts_d[t * 4 + 2] + parts_d[t * 4 + 3];
    as1[(size_t)(m0 + t) * 8 + hb] = s;
    ad1[(size_t)(m0 + t) * 8 + hb] = d;
  }
#pragma unroll
  for (int rep = 0; rep < 4; ++rep) {
    int e = rep * 4096 + t * 8;
    int row = e >> 7, col = e & 127;
    u16x8 v = *(const u16x8*)(ctile + e);
    *(u16x8*)(h1b + (size_t)(m0 + row) * 1024 + hb * 128 + col) = v;
  }
}

// ---- layer-1 gather: XCD-sharded per-head, cheap-ELU all-lane epilogue ----
// Work item = (node-quad q, head c); c = item&7 constant per block when
// gridDim%8==0 -> all blocks touching head c land on one XCD whose L2 holds
// h1b's 2.6MB head-c slice. Wave = 1 node; 4 edge-quads of 16 lanes; lane
// owns 8 channels (16B). Butterfly reduce leaves sums in ALL lanes, so each
// quad finalizes 2 channels (4x fewer epilogue instrs).

__global__ __launch_bounds__(256) void agg1_gather(
    const unsigned short* __restrict__ h1b, const float* __restrict__ as1,
    const float* __restrict__ ad1, const int* __restrict__ offsets,
    const int* __restrict__ list, const float* __restrict__ b1,
    unsigned short* __restrict__ o1pk, int n, int nitems) {
  const int w = threadIdx.x >> 6, lane = threadIdx.x & 63;
  const int quad = lane >> 4, li = lane & 15;

  for (int item = blockIdx.x; item < nitems; item += gridDim.x) {
    const int c = item & 7;   // head / channel chunk
    const int q = item >> 3;  // node quad
    const int node = q * 4 + w;
    if (node >= n) continue;
    const int beg = offsets[node], end = offsets[node + 1];
    const float adc = ad1[(size_t)node * 8 + c];
    const char* hrow = (const char*)h1b + (size_t)c * 256 + (size_t)li * 16;

    float acc[8] = {};
    float den = 0.f;
    int j = beg + quad;
    float a0 = 0.f;
    uint4 v0 = make_uint4(0, 0, 0, 0);
    if (j < end) {
      int s0 = list[j];
      a0 = as1[(size_t)s0 * 8 + c];
      v0 = *(const uint4*)(hrow + ((unsigned)s0 << 11));
    }
    for (; j + 4 < end; j += 4) {
      int s1 = list[j + 4];
      float a1 = as1[(size_t)s1 * 8 + c];
      uint4 v1 = *(const uint4*)(hrow + ((unsigned)s1 << 11));
      float e = __expf(lrelu(a0 + adc));
      den += e;
      fma8h(acc, v0, e);
      a0 = a1; v0 = v1;
    }
    if (j < end) {
      float e = __expf(lrelu(a0 + adc));
      den += e;
      fma8h(acc, v0, e);
    }
    // butterfly reduce across quads -> all 64 lanes hold complete sums
#pragma unroll
    for (int k = 0; k < 8; ++k) {
      acc[k] += __shfl_xor(acc[k], 16);
      acc[k] += __shfl_xor(acc[k], 32);
    }
    den += __shfl_xor(den, 16);
    den += __shfl_xor(den, 32);
    {
      const float inv = 1.f / (den + 1e-16f);
      const int k0 = 2 * quad;  // this quad finalizes channels k0, k0+1
      float va = acc[k0]     * inv + b1[c * 128 + li * 8 + k0];
      float vb = acc[k0 + 1] * inv + b1[c * 128 + li * 8 + k0 + 1];
      va = va > 0.f ? va : __expf(va) - 1.f;  // cheap ELU
      vb = vb > 0.f ? vb : __expf(vb) - 1.f;
      unsigned pk = (unsigned)f2h(va) | ((unsigned)f2h(vb) << 16);
      // packed o1pk write (same formula as gemm2's A-read layout)
      int mb = node >> 6, f = (node >> 4) & 3, l15n = node & 15;
      int ks = 4 * c + (li >> 2), kc = li & 3;
      size_t g = (size_t)(mb * 32 + ks) * 2048 + (size_t)f * 512 +
                 (size_t)(kc * 16 + l15n) * 8 + k0;
      *(unsigned*)(o1pk + g) = pk;
    }
  }
}

// ---- GEMM2 (fp16 MFMA, split-K=4) -----------------------------------------
// BM=64, BN=64, BK=32, 8 K-steps per block. LDS/buf 8KB: [A 4K][B 4K].

__global__ __launch_bounds__(256) void gemm2_splitk(
    const unsigned short* __restrict__ o1pk, const unsigned short* __restrict__ w2pk,
    float* __restrict__ h2p, int Mpad) {
  extern __shared__ char sm[];
  const int t = threadIdx.x, wid = t >> 6, lane = t & 63;
  const int wr = wid >> 1, wc = wid & 1;
  const int mb = blockIdx.x, sk = blockIdx.y;
  const int m0 = mb * 64;
  const int l15 = lane & 15, l4 = lane >> 4;

  f32x4 acc[2][2] = {};

  auto stage = [&](int buf, int ks) {
    char* base0 = sm + buf * 8192;
    const unsigned short* ax = o1pk + (size_t)(mb * 32 + ks) * 2048 + lane * 8;
    const unsigned short* bw = w2pk + (size_t)ks * 2048 + lane * 8;
    GLOAD_LDS16(ax + wid * 512, base0 + wid * 1024);
    GLOAD_LDS16(bw + wid * 512, base0 + 4096 + wid * 1024);
  };

  stage(0, sk * 8);
  __syncthreads();
  int buf = 0;
  for (int step = 0; step < 8; ++step) {
    if (step < 7) stage(buf ^ 1, sk * 8 + step + 1);
    const char* b = sm + buf * 8192;
    f16x8 ah[2], bh[2];
#pragma unroll
    for (int mf = 0; mf < 2; ++mf)
      ah[mf] = *(const f16x8*)(b + (wr * 2 + mf) * 1024 + lane * 16);
#pragma unroll
    for (int nf = 0; nf < 2; ++nf)
      bh[nf] = *(const f16x8*)(b + 4096 + (wc * 2 + nf) * 1024 + lane * 16);
#pragma unroll
    for (int mf = 0; mf < 2; ++mf)
#pragma unroll
      for (int nf = 0; nf < 2; ++nf)
        acc[mf][nf] = __builtin_amdgcn_mfma_f32_16x16x32_f16(ah[mf], bh[nf], acc[mf][nf], 0, 0, 0);
    __syncthreads();
    buf ^= 1;
  }

#pragma unroll
  for (int mf = 0; mf < 2; ++mf)
#pragma unroll
    for (int nf = 0; nf < 2; ++nf)
#pragma unroll
      for (int r = 0; r < 4; ++r) {
        int row = wr * 32 + mf * 16 + l4 * 4 + r;
        int col = wc * 32 + nf * 16 + l15;
        h2p[((size_t)sk * Mpad + m0 + row) * 64 + col] = acc[mf][nf][r];
      }
}

// ---- reduce split-K partials + att2 dots ----------------------------------

__global__ __launch_bounds__(256) void reduce_att2(
    const float* __restrict__ h2p, const float* __restrict__ asrc,
    const float* __restrict__ adst, float* __restrict__ h2,
    float* __restrict__ as2, float* __restrict__ ad2, int Mpad, int n) {
  int w = threadIdx.x >> 6, lane = threadIdx.x & 63;
  int row = blockIdx.x * 4 + w;
  if (row >= n) return;
  float s = 0.f;
#pragma unroll
  for (int sk = 0; sk < 4; ++sk) s += h2p[((size_t)sk * Mpad + row) * 64 + lane];
  h2[(size_t)row * 64 + lane] = s;
  float ds = s * asrc[lane], dd = s * adst[lane];
  for (int o = 32; o; o >>= 1) { ds += __shfl_xor(ds, o); dd += __shfl_xor(dd, o); }
  if (lane == 0) { as2[row] = ds; ad2[row] = dd; }
}

// ---- layer-2 gather: one wave per node, grid-stride -----------------------

__global__ __launch_bounds__(256) void agg2_gather(
    const float* __restrict__ h2, const float* __restrict__ as2,
    const float* __restrict__ ad2, const int* __restrict__ offsets,
    const int* __restrict__ list, const float* __restrict__ b2,
    float* __restrict__ out, int n, int nblk) {
  const int wid = threadIdx.x >> 6, lane = threadIdx.x & 63;
  const int cb = (lane & 15) * 4;  // 4 channels per lane
  const int jo = lane >> 4;        // row-in-quad

  for (int blk = blockIdx.x; blk < nblk; blk += gridDim.x) {
    const int node = blk * 4 + wid;
    if (node >= n) continue;
    const int beg = offsets[node], end = offsets[node + 1];
    const float ad = ad2[node];

    float4 acc = make_float4(0.f, 0.f, 0.f, 0.f);
    float den = 0.f;
    for (int j = beg + jo; j < end; j += 4) {
      int s = list[j];
      float e = __expf(lrelu(as2[s] + ad));
      den += e;
      float4 v = *(const float4*)&h2[(size_t)s * 64 + cb];
      acc.x += e * v.x; acc.y += e * v.y; acc.z += e * v.z; acc.w += e * v.w;
    }
    acc.x += __shfl_xor(acc.x, 16); acc.y += __shfl_xor(acc.y, 16);
    acc.z += __shfl_xor(acc.z, 16); acc.w += __shfl_xor(acc.w, 16);
    den += __shfl_xor(den, 16);
    acc.x += __shfl_xor(acc.x, 32); acc.y += __shfl_xor(acc.y, 32);
    acc.z += __shfl_xor(acc.z, 32); acc.w += __shfl_xor(acc.w, 32);
    den += __shfl_xor(den, 32);
    if (jo == 0) {
      float inv = 1.f / (den + 1e-16f);
      float4 r;
      r.x = acc.x * inv + b2[cb];
      r.y = acc.y * inv + b2[cb + 1];
      r.z = acc.z * inv + b2[cb + 2];
      r.w = acc.w * inv + b2[cb + 3];
      *(float4*)&out[(size_t)node * 64 + cb] = r;
    }
  }
}

// ---------------------------------------------------------------------------

extern "C" void kernel_launch(void* const* d_in, const int* in_sizes, int n_in,
                              void* d_out, int out_size, void* d_ws, size_t ws_size,
                              hipStream_t stream) {
  const float* x     = (const float*)d_in[0];
  const int*   ei    = (const int*)d_in[1];
  const float* W1    = (const float*)d_in[2];
  const float* asrc1 = (const float*)d_in[3];
  const float* adst1 = (const float*)d_in[4];
  const float* b1    = (const float*)d_in[5];
  const float* W2    = (const float*)d_in[6];
  const float* asrc2 = (const float*)d_in[7];
  const float* adst2 = (const float*)d_in[8];
  const float* b2    = (const float*)d_in[9];
  float* out = (float*)d_out;

  const int N = in_sizes[0] / 256;
  const int E = in_sizes[1] / 2;
  const int T = E + N;  // edges + self loops
  const int MBB = (N + 127) / 128;  // gemm1 M-blocks
  const int Mpad = MBB * 128;
  const int MB1 = Mpad / 64;        // 64-row pack blocks
  const int NB = (N + 255) / 256;
  const int NBLK4 = (N + 3) / 4;
  const int NITEMS1 = NBLK4 * 8;    // (node-quad, head) work items
  const int AGG1_GRID = NITEMS1 < 2048 ? NITEMS1 : 2048;  // multiple of 8
  const int AGG2_GRID = NBLK4 < 2048 ? NBLK4 : 2048;

  char* p = (char*)d_ws;
  auto bump = [&](size_t bytes) {
    char* r = p;
    p += (bytes + 255) & ~(size_t)255;
    return r;
  };
  int* counts  = (int*)bump((size_t)N * 4);
  int* offsets = (int*)bump((size_t)(N + 1) * 4);
  int* cursors = (int*)bump((size_t)N * 4);
  int* bsum    = (int*)bump((size_t)NB * 4);
  int* list    = (int*)bump((size_t)T * 4);
  unsigned short* xpk  = (unsigned short*)bump((size_t)Mpad * 256 * 2);   // fp16
  unsigned short* w1pk = (unsigned short*)bump((size_t)1024 * 256 * 2);
  unsigned short* h1b  = (unsigned short*)bump((size_t)Mpad * 1024 * 2);  // fp16
  float* as1           = (float*)bump((size_t)Mpad * 8 * 4);
  float* ad1           = (float*)bump((size_t)Mpad * 8 * 4);
  unsigned short* o1pk = (unsigned short*)bump((size_t)Mpad * 1024 * 2);  // fp16
  unsigned short* w2pk = (unsigned short*)bump((size_t)64 * 1024 * 2);
  float* as2           = (float*)bump((size_t)Mpad * 4);
  float* ad2           = (float*)bump((size_t)Mpad * 4);
  // aliases (safe: single-stream ordering; last reader precedes first writer)
  float* h2p = (float*)h1b;   // 4*Mpad*64*4B = Mpad*1KB <= Mpad*2KB
  float* h2  = (float*)xpk;   // Mpad*64*4B = Mpad*256B <= Mpad*512B

  // CSR + packing
  hipMemsetAsync(counts, 0, (size_t)N * 4, stream);
  {
    int gridsz = (E + 255) / 256 + MB1 * 8 + 64 + 32;
    prep_fused<<<gridsz, 256, 0, stream>>>(ei, counts, E, x, xpk, N, MB1,
                                           W1, w1pk, W2, w2pk);
  }
  scan_blk<<<NB, 256, 0, stream>>>(counts, offsets, bsum, N);
  scan_apply<<<NB, 256, 0, stream>>>(offsets, cursors, bsum, NB, N);
  fill_all<<<(E + N + 255) / 256, 256, 0, stream>>>(ei, cursors, offsets, list, E, N);

  // layer 1
  gemm1_att<<<dim3(MBB, 8), 512, 36864, stream>>>(xpk, w1pk, asrc1, adst1, h1b, as1, ad1);
  agg1_gather<<<AGG1_GRID, 256, 0, stream>>>(h1b, as1, ad1, offsets, list, b1, o1pk, N, NITEMS1);

  // layer 2
  gemm2_splitk<<<dim3(Mpad / 64, 4), 256, 16384, stream>>>(o1pk, w2pk, h2p, Mpad);
  reduce_att2<<<(N + 3) / 4, 256, 0, stream>>>(h2p, asrc2, adst2, h2, as2, ad2, Mpad, N);
  agg2_gather<<<AGG2_GRID, 256, 0, stream>>>(h2, as2, ad2, offsets, list, b2, out, N, NBLK4);
}

// Round 15
// 131.452 us; speedup vs baseline: 1.1119x; 1.0011x over previous
//
#include <hip/hip_runtime.h>
#include <cmath>

// ---------------------------------------------------------------------------
// 2-layer GAT, N=10000, E=160000(+self loops in CSR), F_IN=256 ->
// [8x128 concat]=1024 -> ELU -> [1x64]. All GEMMs single-term fp16 MFMA
// (fp32 accum). agg1: XCD-sharded per-head gather; inner loop written as
// fpext(f16)*f32 fma so the backend can select v_fma_mix_f32; cheap-ELU
// all-lane epilogue.
// ---------------------------------------------------------------------------

typedef _Float16 f16x8 __attribute__((ext_vector_type(8)));
typedef float f32x4 __attribute__((ext_vector_type(4)));
typedef unsigned short u16x8 __attribute__((ext_vector_type(8)));

__device__ __forceinline__ float lrelu(float x) { return x > 0.f ? x : 0.2f * x; }
__device__ __forceinline__ unsigned short f2h(float f) {
  _Float16 h = (_Float16)f;
  return __builtin_bit_cast(unsigned short, h);
}
__device__ __forceinline__ float h2f(unsigned short u) {
  return (float)__builtin_bit_cast(_Float16, u);
}

// acc[k] += e * f16(v)[k] -- written as fma(fpext(h), e, acc) so LLVM can
// select v_fma_mix_f32 (fused unpack+convert+fma). Bit-identical to the
// scalar cvt+fma form.
__device__ __forceinline__ void fma8h(float* acc, uint4 v, float e) {
  f16x8 h = __builtin_bit_cast(f16x8, v);
#pragma unroll
  for (int k = 0; k < 8; ++k) acc[k] = fmaf((float)h[k], e, acc[k]);
}

#define GLOAD_LDS16(gsrc, ldst)                                              \
  __builtin_amdgcn_global_load_lds(                                          \
      (const __attribute__((address_space(1))) unsigned int*)(gsrc),         \
      (__attribute__((address_space(3))) unsigned int*)(ldst), 16, 0, 0)

// ---- fused prep: count (atomics) + pack_x + pack_w1 + pack_w2 (all fp16) --
// Subtile = 16(rows) x 32(k) fp16 = 1024B, lane-linear: lane l supplies
// (row = l&15, kchunk = l>>4), 16B per lane.

__global__ __launch_bounds__(256) void prep_fused(
    const int* __restrict__ ei, int* __restrict__ counts, int E,
    const float* __restrict__ x, unsigned short* __restrict__ xpk, int N, int MB1,
    const float* __restrict__ W1, unsigned short* __restrict__ w1pk,
    const float* __restrict__ W2, unsigned short* __restrict__ w2pk) {
  const int countB = (E + 255) / 256;
  const int pxB = MB1 * 8;
  int bid = blockIdx.x;
  int t = threadIdx.x;

  if (bid < countB) {  // ---- degree count
    int e = bid * 256 + t;
    if (e < E) atomicAdd(&counts[ei[E + e]], 1);
    return;
  }
  bid -= countB;
  if (bid < pxB) {  // ---- pack x (fp16, zero-padded rows)
    int mb = bid >> 3, ks = bid & 7;
    int l = t & 63, f = t >> 6;
    int row = mb * 64 + f * 16 + (l & 15);
    int kc = ks * 32 + (l >> 4) * 8;
    float v[8];
#pragma unroll
    for (int j = 0; j < 8; ++j) v[j] = 0.f;
    if (row < N) {
      const float* xr = x + (size_t)row * 256 + kc;
#pragma unroll
      for (int j = 0; j < 8; ++j) v[j] = xr[j];
    }
    u16x8 hv;
#pragma unroll
    for (int j = 0; j < 8; ++j) hv[j] = f2h(v[j]);
    size_t base = (size_t)(mb * 8 + ks) * 2048;
    *(u16x8*)(xpk + base + (size_t)f * 512 + l * 8) = hv;
    return;
  }
  bid -= pxB;
  if (bid < 64) {  // ---- pack W1^T (fp16)
    int hb = bid >> 3, ks = bid & 7;
    int l = t & 63, gq = t >> 6;
    for (int g = gq; g < 8; g += 4) {
      int n = hb * 128 + g * 16 + (l & 15);
      int k0 = ks * 32 + (l >> 4) * 8;
      u16x8 hv;
#pragma unroll
      for (int j = 0; j < 8; ++j) hv[j] = f2h(W1[(size_t)(k0 + j) * 1024 + n]);
      size_t base = (size_t)(hb * 8 + ks) * 4096;
      *(u16x8*)(w1pk + base + (size_t)g * 512 + l * 8) = hv;
    }
    return;
  }
  bid -= 64;
  {  // ---- pack W2^T (fp16, 32 blocks)
    int ks = bid;
    int l = t & 63, g = t >> 6;
    int n = g * 16 + (l & 15);
    int k0 = ks * 32 + (l >> 4) * 8;
    u16x8 hv;
#pragma unroll
    for (int j = 0; j < 8; ++j) hv[j] = f2h(W2[(size_t)(k0 + j) * 64 + n]);
    size_t base = (size_t)ks * 2048;
    *(u16x8*)(w2pk + base + (size_t)g * 512 + l * 8) = hv;
  }
}

// ---- CSR scan (v[i] = counts[i] + 1 for self loop) ------------------------

__global__ __launch_bounds__(256) void scan_blk(const int* __restrict__ counts,
                                                int* __restrict__ offsets,
                                                int* __restrict__ bsum, int n) {
  __shared__ int lds[256];
  int b = blockIdx.x, t = threadIdx.x, i = b * 256 + t;
  int v = (i < n) ? counts[i] + 1 : 0;
  lds[t] = v;
  __syncthreads();
  for (int off = 1; off < 256; off <<= 1) {
    int tv = (t >= off) ? lds[t - off] : 0;
    __syncthreads();
    lds[t] += tv;
    __syncthreads();
  }
  if (i < n) offsets[i] = lds[t] - v;
  if (t == 255) bsum[b] = lds[255];
}

__global__ __launch_bounds__(256) void scan_apply(int* __restrict__ offsets,
                                                  int* __restrict__ cursors,
                                                  const int* __restrict__ bsum,
                                                  int nb, int n) {
  __shared__ int pre_s;
  int b = blockIdx.x, t = threadIdx.x;
  if (t == 0) {
    int s = 0;
    for (int i = 0; i < b; ++i) s += bsum[i];
    pre_s = s;
    if (b == nb - 1) {
      int tot = s;
      for (int i = b; i < nb; ++i) tot += bsum[i];
      offsets[n] = tot;
    }
  }
  __syncthreads();
  int i = b * 256 + t;
  if (i < n) {
    int o = offsets[i] + pre_s;
    offsets[i] = o;
    cursors[i] = o;
  }
}

__global__ __launch_bounds__(256) void fill_all(const int* __restrict__ ei,
                                                int* __restrict__ cursors,
                                                const int* __restrict__ offsets,
                                                int* __restrict__ list,
                                                int E, int n) {
  int tid = blockIdx.x * 256 + threadIdx.x;
  if (tid < E) {
    int d = ei[E + tid];
    int pos = atomicAdd(&cursors[d], 1);
    list[pos] = ei[tid];
  } else if (tid < E + n) {
    int i = tid - E;
    list[offsets[i + 1] - 1] = i;  // self loop in last slot
  }
}

// ---- GEMM1 (fp16 MFMA) + fused att1 dots ----------------------------------
// BM=128, BN=128 (one head), BK=32, 512 thr (8 waves: 2 row x 4 col).
// LDS per buf 16KB: [A 8K][B 8K]; dbuf = 32KB; epilogue needs 36.9KB.

__global__ __launch_bounds__(512, 4) void gemm1_att(
    const unsigned short* __restrict__ xpk, const unsigned short* __restrict__ w1pk,
    const float* __restrict__ asrc, const float* __restrict__ adst,
    unsigned short* __restrict__ h1b, float* __restrict__ as1,
    float* __restrict__ ad1) {
  extern __shared__ char sm[];
  const int t = threadIdx.x, wid = t >> 6, lane = t & 63;
  const int wr = wid >> 2, wc = wid & 3;
  const int mb = blockIdx.x, hb = blockIdx.y;
  const int m0 = mb * 128;
  const int l15 = lane & 15, l4 = lane >> 4;

  f32x4 acc[4][2] = {};

  auto stage = [&](int buf, int ks) {
    char* base0 = sm + buf * 16384;
    for (int i = wid; i < 16; i += 8) {
      const unsigned short* src;
      int ldsoff;
      if (i < 8) {  // A subtile: pack-block r=i>>2, f=i&3
        int r = i >> 2;
        src = xpk + (size_t)((2 * mb + r) * 8 + ks) * 2048 + (i & 3) * 512 + lane * 8;
        ldsoff = i * 1024;
      } else {  // B subtile g=i-8
        int g = i - 8;
        src = w1pk + (size_t)(hb * 8 + ks) * 4096 + g * 512 + lane * 8;
        ldsoff = 8192 + g * 1024;
      }
      GLOAD_LDS16(src, base0 + ldsoff);
    }
  };

  stage(0, 0);
  __syncthreads();
  int buf = 0;
  for (int step = 0; step < 8; ++step) {
    if (step < 7) stage(buf ^ 1, step + 1);
    const char* b = sm + buf * 16384;
    f16x8 ah[4], bh[2];
#pragma unroll
    for (int mf = 0; mf < 4; ++mf)
      ah[mf] = *(const f16x8*)(b + (wr * 4 + mf) * 1024 + lane * 16);
#pragma unroll
    for (int nf = 0; nf < 2; ++nf)
      bh[nf] = *(const f16x8*)(b + 8192 + (wc * 2 + nf) * 1024 + lane * 16);
#pragma unroll
    for (int mf = 0; mf < 4; ++mf)
#pragma unroll
      for (int nf = 0; nf < 2; ++nf)
        acc[mf][nf] = __builtin_amdgcn_mfma_f32_16x16x32_f16(ah[mf], bh[nf], acc[mf][nf], 0, 0, 0);
    __syncthreads();
    buf ^= 1;
  }

  // epilogue: fused att dots + fp16 C-tile via LDS (coalesced out)
  float* parts_s = (float*)sm;                           // [128][4]
  float* parts_d = (float*)(sm + 2048);                  // [128][4]
  unsigned short* ctile = (unsigned short*)(sm + 4096);  // [128][128]
  float as_c[2], ad_c[2];
#pragma unroll
  for (int nf = 0; nf < 2; ++nf) {
    int col = hb * 128 + wc * 32 + nf * 16 + l15;
    as_c[nf] = asrc[col];
    ad_c[nf] = adst[col];
  }
#pragma unroll
  for (int mf = 0; mf < 4; ++mf) {
    float ss[4] = {0.f, 0.f, 0.f, 0.f}, dd[4] = {0.f, 0.f, 0.f, 0.f};
#pragma unroll
    for (int nf = 0; nf < 2; ++nf)
#pragma unroll
      for (int r = 0; r < 4; ++r) {
        ss[r] += acc[mf][nf][r] * as_c[nf];
        dd[r] += acc[mf][nf][r] * ad_c[nf];
      }
#pragma unroll
    for (int r = 0; r < 4; ++r)
      for (int m = 1; m < 16; m <<= 1) {
        ss[r] += __shfl_xor(ss[r], m);
        dd[r] += __shfl_xor(dd[r], m);
      }
    if (l15 == 0) {
#pragma unroll
      for (int r = 0; r < 4; ++r) {
        int row = wr * 64 + mf * 16 + l4 * 4 + r;
        parts_s[row * 4 + wc] = ss[r];
        parts_d[row * 4 + wc] = dd[r];
      }
    }
#pragma unroll
    for (int nf = 0; nf < 2; ++nf)
#pragma unroll
      for (int r = 0; r < 4; ++r) {
        int row = wr * 64 + mf * 16 + l4 * 4 + r;
        int col = wc * 32 + nf * 16 + l15;
        ctile[row * 128 + col] = f2h(acc[mf][nf][r]);
      }
  }
  __syncthreads();
  if (t < 128) {
    float s = parts_s[t * 4] + parts_s[t * 4 + 1] + parts_s[t * 4 + 2] + parts_s[t * 4 + 3];
    float d = parts_d[t * 4] + parts_d[t * 4 + 1] + parts_d[t * 4 + 2] + parts_d[t * 4 + 3];
    as1[(size_t)(m0 + t) * 8 + hb] = s;
    ad1[(size_t)(m0 + t) * 8 + hb] = d;
  }
#pragma unroll
  for (int rep = 0; rep < 4; ++rep) {
    int e = rep * 4096 + t * 8;
    int row = e >> 7, col = e & 127;
    u16x8 v = *(const u16x8*)(ctile + e);
    *(u16x8*)(h1b + (size_t)(m0 + row) * 1024 + hb * 128 + col) = v;
  }
}

// ---- layer-1 gather: XCD-sharded per-head, cheap-ELU all-lane epilogue ----
// Work item = (node-quad q, head c); c = item&7 constant per block when
// gridDim%8==0 -> all blocks touching head c land on one XCD whose L2 holds
// h1b's 2.6MB head-c slice. Wave = 1 node; 4 edge-quads of 16 lanes; lane
// owns 8 channels (16B). Butterfly reduce leaves sums in ALL lanes; each
// quad finalizes 2 channels.

__global__ __launch_bounds__(256) void agg1_gather(
    const unsigned short* __restrict__ h1b, const float* __restrict__ as1,
    const float* __restrict__ ad1, const int* __restrict__ offsets,
    const int* __restrict__ list, const float* __restrict__ b1,
    unsigned short* __restrict__ o1pk, int n, int nitems) {
  const int w = threadIdx.x >> 6, lane = threadIdx.x & 63;
  const int quad = lane >> 4, li = lane & 15;

  for (int item = blockIdx.x; item < nitems; item += gridDim.x) {
    const int c = item & 7;   // head / channel chunk
    const int q = item >> 3;  // node quad
    const int node = q * 4 + w;
    if (node >= n) continue;
    const int beg = offsets[node], end = offsets[node + 1];
    const float adc = ad1[(size_t)node * 8 + c];
    const char* hrow = (const char*)h1b + (size_t)c * 256 + (size_t)li * 16;

    float acc[8] = {};
    float den = 0.f;
    int j = beg + quad;
    float a0 = 0.f;
    uint4 v0 = make_uint4(0, 0, 0, 0);
    if (j < end) {
      int s0 = list[j];
      a0 = as1[(size_t)s0 * 8 + c];
      v0 = *(const uint4*)(hrow + ((unsigned)s0 << 11));
    }
    for (; j + 4 < end; j += 4) {
      int s1 = list[j + 4];
      float a1 = as1[(size_t)s1 * 8 + c];
      uint4 v1 = *(const uint4*)(hrow + ((unsigned)s1 << 11));
      float e = __expf(lrelu(a0 + adc));
      den += e;
      fma8h(acc, v0, e);
      a0 = a1; v0 = v1;
    }
    if (j < end) {
      float e = __expf(lrelu(a0 + adc));
      den += e;
      fma8h(acc, v0, e);
    }
    // butterfly reduce across quads -> all 64 lanes hold complete sums
#pragma unroll
    for (int k = 0; k < 8; ++k) {
      acc[k] += __shfl_xor(acc[k], 16);
      acc[k] += __shfl_xor(acc[k], 32);
    }
    den += __shfl_xor(den, 16);
    den += __shfl_xor(den, 32);
    {
      const float inv = 1.f / (den + 1e-16f);
      const int k0 = 2 * quad;  // this quad finalizes channels k0, k0+1
      float va = acc[k0]     * inv + b1[c * 128 + li * 8 + k0];
      float vb = acc[k0 + 1] * inv + b1[c * 128 + li * 8 + k0 + 1];
      va = va > 0.f ? va : __expf(va) - 1.f;  // cheap ELU
      vb = vb > 0.f ? vb : __expf(vb) - 1.f;
      unsigned pk = (unsigned)f2h(va) | ((unsigned)f2h(vb) << 16);
      // packed o1pk write (same formula as gemm2's A-read layout)
      int mb = node >> 6, f = (node >> 4) & 3, l15n = node & 15;
      int ks = 4 * c + (li >> 2), kc = li & 3;
      size_t g = (size_t)(mb * 32 + ks) * 2048 + (size_t)f * 512 +
                 (size_t)(kc * 16 + l15n) * 8 + k0;
      *(unsigned*)(o1pk + g) = pk;
    }
  }
}

// ---- GEMM2 (fp16 MFMA, split-K=4) -----------------------------------------
// BM=64, BN=64, BK=32, 8 K-steps per block. LDS/buf 8KB: [A 4K][B 4K].

__global__ __launch_bounds__(256) void gemm2_splitk(
    const unsigned short* __restrict__ o1pk, const unsigned short* __restrict__ w2pk,
    float* __restrict__ h2p, int Mpad) {
  extern __shared__ char sm[];
  const int t = threadIdx.x, wid = t >> 6, lane = t & 63;
  const int wr = wid >> 1, wc = wid & 1;
  const int mb = blockIdx.x, sk = blockIdx.y;
  const int m0 = mb * 64;
  const int l15 = lane & 15, l4 = lane >> 4;

  f32x4 acc[2][2] = {};

  auto stage = [&](int buf, int ks) {
    char* base0 = sm + buf * 8192;
    const unsigned short* ax = o1pk + (size_t)(mb * 32 + ks) * 2048 + lane * 8;
    const unsigned short* bw = w2pk + (size_t)ks * 2048 + lane * 8;
    GLOAD_LDS16(ax + wid * 512, base0 + wid * 1024);
    GLOAD_LDS16(bw + wid * 512, base0 + 4096 + wid * 1024);
  };

  stage(0, sk * 8);
  __syncthreads();
  int buf = 0;
  for (int step = 0; step < 8; ++step) {
    if (step < 7) stage(buf ^ 1, sk * 8 + step + 1);
    const char* b = sm + buf * 8192;
    f16x8 ah[2], bh[2];
#pragma unroll
    for (int mf = 0; mf < 2; ++mf)
      ah[mf] = *(const f16x8*)(b + (wr * 2 + mf) * 1024 + lane * 16);
#pragma unroll
    for (int nf = 0; nf < 2; ++nf)
      bh[nf] = *(const f16x8*)(b + 4096 + (wc * 2 + nf) * 1024 + lane * 16);
#pragma unroll
    for (int mf = 0; mf < 2; ++mf)
#pragma unroll
      for (int nf = 0; nf < 2; ++nf)
        acc[mf][nf] = __builtin_amdgcn_mfma_f32_16x16x32_f16(ah[mf], bh[nf], acc[mf][nf], 0, 0, 0);
    __syncthreads();
    buf ^= 1;
  }

#pragma unroll
  for (int mf = 0; mf < 2; ++mf)
#pragma unroll
    for (int nf = 0; nf < 2; ++nf)
#pragma unroll
      for (int r = 0; r < 4; ++r) {
        int row = wr * 32 + mf * 16 + l4 * 4 + r;
        int col = wc * 32 + nf * 16 + l15;
        h2p[((size_t)sk * Mpad + m0 + row) * 64 + col] = acc[mf][nf][r];
      }
}

// ---- reduce split-K partials + att2 dots ----------------------------------

__global__ __launch_bounds__(256) void reduce_att2(
    const float* __restrict__ h2p, const float* __restrict__ asrc,
    const float* __restrict__ adst, float* __restrict__ h2,
    float* __restrict__ as2, float* __restrict__ ad2, int Mpad, int n) {
  int w = threadIdx.x >> 6, lane = threadIdx.x & 63;
  int row = blockIdx.x * 4 + w;
  if (row >= n) return;
  float s = 0.f;
#pragma unroll
  for (int sk = 0; sk < 4; ++sk) s += h2p[((size_t)sk * Mpad + row) * 64 + lane];
  h2[(size_t)row * 64 + lane] = s;
  float ds = s * asrc[lane], dd = s * adst[lane];
  for (int o = 32; o; o >>= 1) { ds += __shfl_xor(ds, o); dd += __shfl_xor(dd, o); }
  if (lane == 0) { as2[row] = ds; ad2[row] = dd; }
}

// ---- layer-2 gather: one wave per node, grid-stride -----------------------

__global__ __launch_bounds__(256) void agg2_gather(
    const float* __restrict__ h2, const float* __restrict__ as2,
    const float* __restrict__ ad2, const int* __restrict__ offsets,
    const int* __restrict__ list, const float* __restrict__ b2,
    float* __restrict__ out, int n, int nblk) {
  const int wid = threadIdx.x >> 6, lane = threadIdx.x & 63;
  const int cb = (lane & 15) * 4;  // 4 channels per lane
  const int jo = lane >> 4;        // row-in-quad

  for (int blk = blockIdx.x; blk < nblk; blk += gridDim.x) {
    const int node = blk * 4 + wid;
    if (node >= n) continue;
    const int beg = offsets[node], end = offsets[node + 1];
    const float ad = ad2[node];

    float4 acc = make_float4(0.f, 0.f, 0.f, 0.f);
    float den = 0.f;
    for (int j = beg + jo; j < end; j += 4) {
      int s = list[j];
      float e = __expf(lrelu(as2[s] + ad));
      den += e;
      float4 v = *(const float4*)&h2[(size_t)s * 64 + cb];
      acc.x += e * v.x; acc.y += e * v.y; acc.z += e * v.z; acc.w += e * v.w;
    }
    acc.x += __shfl_xor(acc.x, 16); acc.y += __shfl_xor(acc.y, 16);
    acc.z += __shfl_xor(acc.z, 16); acc.w += __shfl_xor(acc.w, 16);
    den += __shfl_xor(den, 16);
    acc.x += __shfl_xor(acc.x, 32); acc.y += __shfl_xor(acc.y, 32);
    acc.z += __shfl_xor(acc.z, 32); acc.w += __shfl_xor(acc.w, 32);
    den += __shfl_xor(den, 32);
    if (jo == 0) {
      float inv = 1.f / (den + 1e-16f);
      float4 r;
      r.x = acc.x * inv + b2[cb];
      r.y = acc.y * inv + b2[cb + 1];
      r.z = acc.z * inv + b2[cb + 2];
      r.w = acc.w * inv + b2[cb + 3];
      *(float4*)&out[(size_t)node * 64 + cb] = r;
    }
  }
}

// ---------------------------------------------------------------------------

extern "C" void kernel_launch(void* const* d_in, const int* in_sizes, int n_in,
                              void* d_out, int out_size, void* d_ws, size_t ws_size,
                              hipStream_t stream) {
  const float* x     = (const float*)d_in[0];
  const int*   ei    = (const int*)d_in[1];
  const float* W1    = (const float*)d_in[2];
  const float* asrc1 = (const float*)d_in[3];
  const float* adst1 = (const float*)d_in[4];
  const float* b1    = (const float*)d_in[5];
  const float* W2    = (const float*)d_in[6];
  const float* asrc2 = (const float*)d_in[7];
  const float* adst2 = (const float*)d_in[8];
  const float* b2    = (const float*)d_in[9];
  float* out = (float*)d_out;

  const int N = in_sizes[0] / 256;
  const int E = in_sizes[1] / 2;
  const int T = E + N;  // edges + self loops
  const int MBB = (N + 127) / 128;  // gemm1 M-blocks
  const int Mpad = MBB * 128;
  const int MB1 = Mpad / 64;        // 64-row pack blocks
  const int NB = (N + 255) / 256;
  const int NBLK4 = (N + 3) / 4;
  const int NITEMS1 = NBLK4 * 8;    // (node-quad, head) work items
  const int AGG1_GRID = NITEMS1 < 2048 ? NITEMS1 : 2048;  // multiple of 8
  const int AGG2_GRID = NBLK4 < 2048 ? NBLK4 : 2048;

  char* p = (char*)d_ws;
  auto bump = [&](size_t bytes) {
    char* r = p;
    p += (bytes + 255) & ~(size_t)255;
    return r;
  };
  int* counts  = (int*)bump((size_t)N * 4);
  int* offsets = (int*)bump((size_t)(N + 1) * 4);
  int* cursors = (int*)bump((size_t)N * 4);
  int* bsum    = (int*)bump((size_t)NB * 4);
  int* list    = (int*)bump((size_t)T * 4);
  unsigned short* xpk  = (unsigned short*)bump((size_t)Mpad * 256 * 2);   // fp16
  unsigned short* w1pk = (unsigned short*)bump((size_t)1024 * 256 * 2);
  unsigned short* h1b  = (unsigned short*)bump((size_t)Mpad * 1024 * 2);  // fp16
  float* as1           = (float*)bump((size_t)Mpad * 8 * 4);
  float* ad1           = (float*)bump((size_t)Mpad * 8 * 4);
  unsigned short* o1pk = (unsigned short*)bump((size_t)Mpad * 1024 * 2);  // fp16
  unsigned short* w2pk = (unsigned short*)bump((size_t)64 * 1024 * 2);
  float* as2           = (float*)bump((size_t)Mpad * 4);
  float* ad2           = (float*)bump((size_t)Mpad * 4);
  // aliases (safe: single-stream ordering; last reader precedes first writer)
  float* h2p = (float*)h1b;   // 4*Mpad*64*4B = Mpad*1KB <= Mpad*2KB
  float* h2  = (float*)xpk;   // Mpad*64*4B = Mpad*256B <= Mpad*512B

  // CSR + packing
  hipMemsetAsync(counts, 0, (size_t)N * 4, stream);
  {
    int gridsz = (E + 255) / 256 + MB1 * 8 + 64 + 32;
    prep_fused<<<gridsz, 256, 0, stream>>>(ei, counts, E, x, xpk, N, MB1,
                                           W1, w1pk, W2, w2pk);
  }
  scan_blk<<<NB, 256, 0, stream>>>(counts, offsets, bsum, N);
  scan_apply<<<NB, 256, 0, stream>>>(offsets, cursors, bsum, NB, N);
  fill_all<<<(E + N + 255) / 256, 256, 0, stream>>>(ei, cursors, offsets, list, E, N);

  // layer 1
  gemm1_att<<<dim3(MBB, 8), 512, 36864, stream>>>(xpk, w1pk, asrc1, adst1, h1b, as1, ad1);
  agg1_gather<<<AGG1_GRID, 256, 0, stream>>>(h1b, as1, ad1, offsets, list, b1, o1pk, N, NITEMS1);

  // layer 2
  gemm2_splitk<<<dim3(Mpad / 64, 4), 256, 16384, stream>>>(o1pk, w2pk, h2p, Mpad);
  reduce_att2<<<(N + 3) / 4, 256, 0, stream>>>(h2p, asrc2, adst2, h2, as2, ad2, Mpad, N);
  agg2_gather<<<AGG2_GRID, 256, 0, stream>>>(h2, as2, ad2, offsets, list, b2, out, N, NBLK4);
}

// Round 16
// 130.455 us; speedup vs baseline: 1.1204x; 1.0076x over previous
//
#include <hip/hip_runtime.h>
#include <cmath>

// ---------------------------------------------------------------------------
// 2-layer GAT, N=10000, E=160000(+self loops in CSR), F_IN=256 ->
// [8x128 concat]=1024 -> ELU -> [1x64]. All GEMMs single-term fp16 MFMA
// (fp32 accum). agg1: XCD-sharded per-head gather, one block per item,
// decoupled 2-stage pipeline, cheap-ELU all-lane epilogue.
// ---------------------------------------------------------------------------

typedef _Float16 f16x8 __attribute__((ext_vector_type(8)));
typedef float f32x4 __attribute__((ext_vector_type(4)));
typedef unsigned short u16x8 __attribute__((ext_vector_type(8)));

__device__ __forceinline__ float lrelu(float x) { return x > 0.f ? x : 0.2f * x; }
__device__ __forceinline__ unsigned short f2h(float f) {
  _Float16 h = (_Float16)f;
  return __builtin_bit_cast(unsigned short, h);
}
__device__ __forceinline__ float h2f(unsigned short u) {
  return (float)__builtin_bit_cast(_Float16, u);
}

__device__ __forceinline__ void fma8h(float* acc, uint4 v, float e) {
  f16x8 h = __builtin_bit_cast(f16x8, v);
#pragma unroll
  for (int k = 0; k < 8; ++k) acc[k] = fmaf((float)h[k], e, acc[k]);
}

#define GLOAD_LDS16(gsrc, ldst)                                              \
  __builtin_amdgcn_global_load_lds(                                          \
      (const __attribute__((address_space(1))) unsigned int*)(gsrc),         \
      (__attribute__((address_space(3))) unsigned int*)(ldst), 16, 0, 0)

// ---- fused prep: count (atomics) + pack_x + pack_w1 + pack_w2 (all fp16) --

__global__ __launch_bounds__(256) void prep_fused(
    const int* __restrict__ ei, int* __restrict__ counts, int E,
    const float* __restrict__ x, unsigned short* __restrict__ xpk, int N, int MB1,
    const float* __restrict__ W1, unsigned short* __restrict__ w1pk,
    const float* __restrict__ W2, unsigned short* __restrict__ w2pk) {
  const int countB = (E + 255) / 256;
  const int pxB = MB1 * 8;
  int bid = blockIdx.x;
  int t = threadIdx.x;

  if (bid < countB) {  // ---- degree count
    int e = bid * 256 + t;
    if (e < E) atomicAdd(&counts[ei[E + e]], 1);
    return;
  }
  bid -= countB;
  if (bid < pxB) {  // ---- pack x (fp16, zero-padded rows)
    int mb = bid >> 3, ks = bid & 7;
    int l = t & 63, f = t >> 6;
    int row = mb * 64 + f * 16 + (l & 15);
    int kc = ks * 32 + (l >> 4) * 8;
    float v[8];
#pragma unroll
    for (int j = 0; j < 8; ++j) v[j] = 0.f;
    if (row < N) {
      const float* xr = x + (size_t)row * 256 + kc;
#pragma unroll
      for (int j = 0; j < 8; ++j) v[j] = xr[j];
    }
    u16x8 hv;
#pragma unroll
    for (int j = 0; j < 8; ++j) hv[j] = f2h(v[j]);
    size_t base = (size_t)(mb * 8 + ks) * 2048;
    *(u16x8*)(xpk + base + (size_t)f * 512 + l * 8) = hv;
    return;
  }
  bid -= pxB;
  if (bid < 64) {  // ---- pack W1^T (fp16)
    int hb = bid >> 3, ks = bid & 7;
    int l = t & 63, gq = t >> 6;
    for (int g = gq; g < 8; g += 4) {
      int n = hb * 128 + g * 16 + (l & 15);
      int k0 = ks * 32 + (l >> 4) * 8;
      u16x8 hv;
#pragma unroll
      for (int j = 0; j < 8; ++j) hv[j] = f2h(W1[(size_t)(k0 + j) * 1024 + n]);
      size_t base = (size_t)(hb * 8 + ks) * 4096;
      *(u16x8*)(w1pk + base + (size_t)g * 512 + l * 8) = hv;
    }
    return;
  }
  bid -= 64;
  {  // ---- pack W2^T (fp16, 32 blocks)
    int ks = bid;
    int l = t & 63, g = t >> 6;
    int n = g * 16 + (l & 15);
    int k0 = ks * 32 + (l >> 4) * 8;
    u16x8 hv;
#pragma unroll
    for (int j = 0; j < 8; ++j) hv[j] = f2h(W2[(size_t)(k0 + j) * 64 + n]);
    size_t base = (size_t)ks * 2048;
    *(u16x8*)(w2pk + base + (size_t)g * 512 + l * 8) = hv;
  }
}

// ---- CSR scan (v[i] = counts[i] + 1 for self loop) ------------------------

__global__ __launch_bounds__(256) void scan_blk(const int* __restrict__ counts,
                                                int* __restrict__ offsets,
                                                int* __restrict__ bsum, int n) {
  __shared__ int lds[256];
  int b = blockIdx.x, t = threadIdx.x, i = b * 256 + t;
  int v = (i < n) ? counts[i] + 1 : 0;
  lds[t] = v;
  __syncthreads();
  for (int off = 1; off < 256; off <<= 1) {
    int tv = (t >= off) ? lds[t - off] : 0;
    __syncthreads();
    lds[t] += tv;
    __syncthreads();
  }
  if (i < n) offsets[i] = lds[t] - v;
  if (t == 255) bsum[b] = lds[255];
}

__global__ __launch_bounds__(256) void scan_apply(int* __restrict__ offsets,
                                                  int* __restrict__ cursors,
                                                  const int* __restrict__ bsum,
                                                  int nb, int n) {
  __shared__ int pre_s;
  int b = blockIdx.x, t = threadIdx.x;
  if (t == 0) {
    int s = 0;
    for (int i = 0; i < b; ++i) s += bsum[i];
    pre_s = s;
    if (b == nb - 1) {
      int tot = s;
      for (int i = b; i < nb; ++i) tot += bsum[i];
      offsets[n] = tot;
    }
  }
  __syncthreads();
  int i = b * 256 + t;
  if (i < n) {
    int o = offsets[i] + pre_s;
    offsets[i] = o;
    cursors[i] = o;
  }
}

__global__ __launch_bounds__(256) void fill_all(const int* __restrict__ ei,
                                                int* __restrict__ cursors,
                                                const int* __restrict__ offsets,
                                                int* __restrict__ list,
                                                int E, int n) {
  int tid = blockIdx.x * 256 + threadIdx.x;
  if (tid < E) {
    int d = ei[E + tid];
    int pos = atomicAdd(&cursors[d], 1);
    list[pos] = ei[tid];
  } else if (tid < E + n) {
    int i = tid - E;
    list[offsets[i + 1] - 1] = i;  // self loop in last slot
  }
}

// ---- GEMM1 (fp16 MFMA) + fused att1 dots ----------------------------------
// BM=128, BN=128 (one head), BK=32, 512 thr (8 waves: 2 row x 4 col).

__global__ __launch_bounds__(512, 4) void gemm1_att(
    const unsigned short* __restrict__ xpk, const unsigned short* __restrict__ w1pk,
    const float* __restrict__ asrc, const float* __restrict__ adst,
    unsigned short* __restrict__ h1b, float* __restrict__ as1,
    float* __restrict__ ad1) {
  extern __shared__ char sm[];
  const int t = threadIdx.x, wid = t >> 6, lane = t & 63;
  const int wr = wid >> 2, wc = wid & 3;
  const int mb = blockIdx.x, hb = blockIdx.y;
  const int m0 = mb * 128;
  const int l15 = lane & 15, l4 = lane >> 4;

  f32x4 acc[4][2] = {};

  auto stage = [&](int buf, int ks) {
    char* base0 = sm + buf * 16384;
    for (int i = wid; i < 16; i += 8) {
      const unsigned short* src;
      int ldsoff;
      if (i < 8) {  // A subtile: pack-block r=i>>2, f=i&3
        int r = i >> 2;
        src = xpk + (size_t)((2 * mb + r) * 8 + ks) * 2048 + (i & 3) * 512 + lane * 8;
        ldsoff = i * 1024;
      } else {  // B subtile g=i-8
        int g = i - 8;
        src = w1pk + (size_t)(hb * 8 + ks) * 4096 + g * 512 + lane * 8;
        ldsoff = 8192 + g * 1024;
      }
      GLOAD_LDS16(src, base0 + ldsoff);
    }
  };

  stage(0, 0);
  __syncthreads();
  int buf = 0;
  for (int step = 0; step < 8; ++step) {
    if (step < 7) stage(buf ^ 1, step + 1);
    const char* b = sm + buf * 16384;
    f16x8 ah[4], bh[2];
#pragma unroll
    for (int mf = 0; mf < 4; ++mf)
      ah[mf] = *(const f16x8*)(b + (wr * 4 + mf) * 1024 + lane * 16);
#pragma unroll
    for (int nf = 0; nf < 2; ++nf)
      bh[nf] = *(const f16x8*)(b + 8192 + (wc * 2 + nf) * 1024 + lane * 16);
#pragma unroll
    for (int mf = 0; mf < 4; ++mf)
#pragma unroll
      for (int nf = 0; nf < 2; ++nf)
        acc[mf][nf] = __builtin_amdgcn_mfma_f32_16x16x32_f16(ah[mf], bh[nf], acc[mf][nf], 0, 0, 0);
    __syncthreads();
    buf ^= 1;
  }

  // epilogue: fused att dots + fp16 C-tile via LDS (coalesced out)
  float* parts_s = (float*)sm;                           // [128][4]
  float* parts_d = (float*)(sm + 2048);                  // [128][4]
  unsigned short* ctile = (unsigned short*)(sm + 4096);  // [128][128]
  float as_c[2], ad_c[2];
#pragma unroll
  for (int nf = 0; nf < 2; ++nf) {
    int col = hb * 128 + wc * 32 + nf * 16 + l15;
    as_c[nf] = asrc[col];
    ad_c[nf] = adst[col];
  }
#pragma unroll
  for (int mf = 0; mf < 4; ++mf) {
    float ss[4] = {0.f, 0.f, 0.f, 0.f}, dd[4] = {0.f, 0.f, 0.f, 0.f};
#pragma unroll
    for (int nf = 0; nf < 2; ++nf)
#pragma unroll
      for (int r = 0; r < 4; ++r) {
        ss[r] += acc[mf][nf][r] * as_c[nf];
        dd[r] += acc[mf][nf][r] * ad_c[nf];
      }
#pragma unroll
    for (int r = 0; r < 4; ++r)
      for (int m = 1; m < 16; m <<= 1) {
        ss[r] += __shfl_xor(ss[r], m);
        dd[r] += __shfl_xor(dd[r], m);
      }
    if (l15 == 0) {
#pragma unroll
      for (int r = 0; r < 4; ++r) {
        int row = wr * 64 + mf * 16 + l4 * 4 + r;
        parts_s[row * 4 + wc] = ss[r];
        parts_d[row * 4 + wc] = dd[r];
      }
    }
#pragma unroll
    for (int nf = 0; nf < 2; ++nf)
#pragma unroll
      for (int r = 0; r < 4; ++r) {
        int row = wr * 64 + mf * 16 + l4 * 4 + r;
        int col = wc * 32 + nf * 16 + l15;
        ctile[row * 128 + col] = f2h(acc[mf][nf][r]);
      }
  }
  __syncthreads();
  if (t < 128) {
    float s = parts_s[t * 4] + parts_s[t * 4 + 1] + parts_s[t * 4 + 2] + parts_s[t * 4 + 3];
    float d = parts_d[t * 4] + parts_d[t * 4 + 1] + parts_d[t * 4 + 2] + parts_d[t * 4 + 3];
    as1[(size_t)(m0 + t) * 8 + hb] = s;
    ad1[(size_t)(m0 + t) * 8 + hb] = d;
  }
#pragma unroll
  for (int rep = 0; rep < 4; ++rep) {
    int e = rep * 4096 + t * 8;
    int row = e >> 7, col = e & 127;
    u16x8 v = *(const u16x8*)(ctile + e);
    *(u16x8*)(h1b + (size_t)(m0 + row) * 1024 + hb * 128 + col) = v;
  }
}

// ---- layer-1 gather: XCD-sharded per-head, 1 block/item, 2-stage pipe -----
// Block = item (node-quad q, head c); c = blockIdx&7 (grid%8==0) -> all
// blocks touching head c land on one XCD whose L2 holds h1b's 2.6MB slice.
// Wave = 1 node; 4 edge-quads of 16 lanes; lane owns 8 channels (16B).
// Index queue 2 steps ahead, att+row data 1 step ahead.

__global__ __launch_bounds__(256) void agg1_gather(
    const unsigned short* __restrict__ h1b, const float* __restrict__ as1,
    const float* __restrict__ ad1, const int* __restrict__ offsets,
    const int* __restrict__ list, const float* __restrict__ b1,
    unsigned short* __restrict__ o1pk, int n) {
  const int w = threadIdx.x >> 6, lane = threadIdx.x & 63;
  const int quad = lane >> 4, li = lane & 15;

  const int c = blockIdx.x & 7;   // head / channel chunk
  const int q = blockIdx.x >> 3;  // node quad
  const int node = q * 4 + w;
  if (node >= n) return;
  const int beg = offsets[node], end = offsets[node + 1];
  const float adc = ad1[(size_t)node * 8 + c];
  const char* hrow = (const char*)h1b + (size_t)c * 256 + (size_t)li * 16;

  float acc[8] = {};
  float den = 0.f;
  int j = beg + quad;
  int s1 = 0;
  float a0 = 0.f;
  uint4 v0 = make_uint4(0, 0, 0, 0);
  if (j < end) {
    int s0 = list[j];
    if (j + 4 < end) s1 = list[j + 4];
    a0 = as1[(size_t)s0 * 8 + c];
    v0 = *(const uint4*)(hrow + ((unsigned)s0 << 11));
  }
  for (; j + 4 < end; j += 4) {
    int s2 = (j + 8 < end) ? list[j + 8] : 0;     // index 2 ahead
    float a1 = as1[(size_t)s1 * 8 + c];            // data 1 ahead
    uint4 v1 = *(const uint4*)(hrow + ((unsigned)s1 << 11));
    float e = __expf(lrelu(a0 + adc));             // compute current
    den += e;
    fma8h(acc, v0, e);
    s1 = s2; a0 = a1; v0 = v1;
  }
  if (j < end) {
    float e = __expf(lrelu(a0 + adc));
    den += e;
    fma8h(acc, v0, e);
  }
  // butterfly reduce across quads -> all 64 lanes hold complete sums
#pragma unroll
  for (int k = 0; k < 8; ++k) {
    acc[k] += __shfl_xor(acc[k], 16);
    acc[k] += __shfl_xor(acc[k], 32);
  }
  den += __shfl_xor(den, 16);
  den += __shfl_xor(den, 32);
  {
    const float inv = 1.f / (den + 1e-16f);
    const int k0 = 2 * quad;  // this quad finalizes channels k0, k0+1
    float va = acc[k0]     * inv + b1[c * 128 + li * 8 + k0];
    float vb = acc[k0 + 1] * inv + b1[c * 128 + li * 8 + k0 + 1];
    va = va > 0.f ? va : __expf(va) - 1.f;  // cheap ELU
    vb = vb > 0.f ? vb : __expf(vb) - 1.f;
    unsigned pk = (unsigned)f2h(va) | ((unsigned)f2h(vb) << 16);
    // packed o1pk write (same formula as gemm2's A-read layout)
    int mb = node >> 6, f = (node >> 4) & 3, l15n = node & 15;
    int ks = 4 * c + (li >> 2), kc = li & 3;
    size_t g = (size_t)(mb * 32 + ks) * 2048 + (size_t)f * 512 +
               (size_t)(kc * 16 + l15n) * 8 + k0;
    *(unsigned*)(o1pk + g) = pk;
  }
}

// ---- GEMM2 (fp16 MFMA, split-K=4) -----------------------------------------

__global__ __launch_bounds__(256) void gemm2_splitk(
    const unsigned short* __restrict__ o1pk, const unsigned short* __restrict__ w2pk,
    float* __restrict__ h2p, int Mpad) {
  extern __shared__ char sm[];
  const int t = threadIdx.x, wid = t >> 6, lane = t & 63;
  const int wr = wid >> 1, wc = wid & 1;
  const int mb = blockIdx.x, sk = blockIdx.y;
  const int m0 = mb * 64;
  const int l15 = lane & 15, l4 = lane >> 4;

  f32x4 acc[2][2] = {};

  auto stage = [&](int buf, int ks) {
    char* base0 = sm + buf * 8192;
    const unsigned short* ax = o1pk + (size_t)(mb * 32 + ks) * 2048 + lane * 8;
    const unsigned short* bw = w2pk + (size_t)ks * 2048 + lane * 8;
    GLOAD_LDS16(ax + wid * 512, base0 + wid * 1024);
    GLOAD_LDS16(bw + wid * 512, base0 + 4096 + wid * 1024);
  };

  stage(0, sk * 8);
  __syncthreads();
  int buf = 0;
  for (int step = 0; step < 8; ++step) {
    if (step < 7) stage(buf ^ 1, sk * 8 + step + 1);
    const char* b = sm + buf * 8192;
    f16x8 ah[2], bh[2];
#pragma unroll
    for (int mf = 0; mf < 2; ++mf)
      ah[mf] = *(const f16x8*)(b + (wr * 2 + mf) * 1024 + lane * 16);
#pragma unroll
    for (int nf = 0; nf < 2; ++nf)
      bh[nf] = *(const f16x8*)(b + 4096 + (wc * 2 + nf) * 1024 + lane * 16);
#pragma unroll
    for (int mf = 0; mf < 2; ++mf)
#pragma unroll
      for (int nf = 0; nf < 2; ++nf)
        acc[mf][nf] = __builtin_amdgcn_mfma_f32_16x16x32_f16(ah[mf], bh[nf], acc[mf][nf], 0, 0, 0);
    __syncthreads();
    buf ^= 1;
  }

#pragma unroll
  for (int mf = 0; mf < 2; ++mf)
#pragma unroll
    for (int nf = 0; nf < 2; ++nf)
#pragma unroll
      for (int r = 0; r < 4; ++r) {
        int row = wr * 32 + mf * 16 + l4 * 4 + r;
        int col = wc * 32 + nf * 16 + l15;
        h2p[((size_t)sk * Mpad + m0 + row) * 64 + col] = acc[mf][nf][r];
      }
}

// ---- reduce split-K partials + att2 dots ----------------------------------

__global__ __launch_bounds__(256) void reduce_att2(
    const float* __restrict__ h2p, const float* __restrict__ asrc,
    const float* __restrict__ adst, float* __restrict__ h2,
    float* __restrict__ as2, float* __restrict__ ad2, int Mpad, int n) {
  int w = threadIdx.x >> 6, lane = threadIdx.x & 63;
  int row = blockIdx.x * 4 + w;
  if (row >= n) return;
  float s = 0.f;
#pragma unroll
  for (int sk = 0; sk < 4; ++sk) s += h2p[((size_t)sk * Mpad + row) * 64 + lane];
  h2[(size_t)row * 64 + lane] = s;
  float ds = s * asrc[lane], dd = s * adst[lane];
  for (int o = 32; o; o >>= 1) { ds += __shfl_xor(ds, o); dd += __shfl_xor(dd, o); }
  if (lane == 0) { as2[row] = ds; ad2[row] = dd; }
}

// ---- layer-2 gather: one wave per node, 1 block per quad ------------------

__global__ __launch_bounds__(256) void agg2_gather(
    const float* __restrict__ h2, const float* __restrict__ as2,
    const float* __restrict__ ad2, const int* __restrict__ offsets,
    const int* __restrict__ list, const float* __restrict__ b2,
    float* __restrict__ out, int n) {
  const int wid = threadIdx.x >> 6, lane = threadIdx.x & 63;
  const int cb = (lane & 15) * 4;  // 4 channels per lane
  const int jo = lane >> 4;        // row-in-quad

  const int node = blockIdx.x * 4 + wid;
  if (node >= n) return;
  const int beg = offsets[node], end = offsets[node + 1];
  const float ad = ad2[node];

  float4 acc = make_float4(0.f, 0.f, 0.f, 0.f);
  float den = 0.f;
  for (int j = beg + jo; j < end; j += 4) {
    int s = list[j];
    float e = __expf(lrelu(as2[s] + ad));
    den += e;
    float4 v = *(const float4*)&h2[(size_t)s * 64 + cb];
    acc.x += e * v.x; acc.y += e * v.y; acc.z += e * v.z; acc.w += e * v.w;
  }
  acc.x += __shfl_xor(acc.x, 16); acc.y += __shfl_xor(acc.y, 16);
  acc.z += __shfl_xor(acc.z, 16); acc.w += __shfl_xor(acc.w, 16);
  den += __shfl_xor(den, 16);
  acc.x += __shfl_xor(acc.x, 32); acc.y += __shfl_xor(acc.y, 32);
  acc.z += __shfl_xor(acc.z, 32); acc.w += __shfl_xor(acc.w, 32);
  den += __shfl_xor(den, 32);
  if (jo == 0) {
    float inv = 1.f / (den + 1e-16f);
    float4 r;
    r.x = acc.x * inv + b2[cb];
    r.y = acc.y * inv + b2[cb + 1];
    r.z = acc.z * inv + b2[cb + 2];
    r.w = acc.w * inv + b2[cb + 3];
    *(float4*)&out[(size_t)node * 64 + cb] = r;
  }
}

// ---------------------------------------------------------------------------

extern "C" void kernel_launch(void* const* d_in, const int* in_sizes, int n_in,
                              void* d_out, int out_size, void* d_ws, size_t ws_size,
                              hipStream_t stream) {
  const float* x     = (const float*)d_in[0];
  const int*   ei    = (const int*)d_in[1];
  const float* W1    = (const float*)d_in[2];
  const float* asrc1 = (const float*)d_in[3];
  const float* adst1 = (const float*)d_in[4];
  const float* b1    = (const float*)d_in[5];
  const float* W2    = (const float*)d_in[6];
  const float* asrc2 = (const float*)d_in[7];
  const float* adst2 = (const float*)d_in[8];
  const float* b2    = (const float*)d_in[9];
  float* out = (float*)d_out;

  const int N = in_sizes[0] / 256;
  const int E = in_sizes[1] / 2;
  const int T = E + N;  // edges + self loops
  const int MBB = (N + 127) / 128;  // gemm1 M-blocks
  const int Mpad = MBB * 128;
  const int MB1 = Mpad / 64;        // 64-row pack blocks
  const int NB = (N + 255) / 256;
  const int NBLK4 = (N + 3) / 4;
  const int NITEMS1 = NBLK4 * 8;    // (node-quad, head) work items, %8==0

  char* p = (char*)d_ws;
  auto bump = [&](size_t bytes) {
    char* r = p;
    p += (bytes + 255) & ~(size_t)255;
    return r;
  };
  int* counts  = (int*)bump((size_t)N * 4);
  int* offsets = (int*)bump((size_t)(N + 1) * 4);
  int* cursors = (int*)bump((size_t)N * 4);
  int* bsum    = (int*)bump((size_t)NB * 4);
  int* list    = (int*)bump((size_t)T * 4);
  unsigned short* xpk  = (unsigned short*)bump((size_t)Mpad * 256 * 2);   // fp16
  unsigned short* w1pk = (unsigned short*)bump((size_t)1024 * 256 * 2);
  unsigned short* h1b  = (unsigned short*)bump((size_t)Mpad * 1024 * 2);  // fp16
  float* as1           = (float*)bump((size_t)Mpad * 8 * 4);
  float* ad1           = (float*)bump((size_t)Mpad * 8 * 4);
  unsigned short* o1pk = (unsigned short*)bump((size_t)Mpad * 1024 * 2);  // fp16
  unsigned short* w2pk = (unsigned short*)bump((size_t)64 * 1024 * 2);
  float* as2           = (float*)bump((size_t)Mpad * 4);
  float* ad2           = (float*)bump((size_t)Mpad * 4);
  // aliases (safe: single-stream ordering; last reader precedes first writer)
  float* h2p = (float*)h1b;   // 4*Mpad*64*4B = Mpad*1KB <= Mpad*2KB
  float* h2  = (float*)xpk;   // Mpad*64*4B = Mpad*256B <= Mpad*512B

  // CSR + packing
  hipMemsetAsync(counts, 0, (size_t)N * 4, stream);
  {
    int gridsz = (E + 255) / 256 + MB1 * 8 + 64 + 32;
    prep_fused<<<gridsz, 256, 0, stream>>>(ei, counts, E, x, xpk, N, MB1,
                                           W1, w1pk, W2, w2pk);
  }
  scan_blk<<<NB, 256, 0, stream>>>(counts, offsets, bsum, N);
  scan_apply<<<NB, 256, 0, stream>>>(offsets, cursors, bsum, NB, N);
  fill_all<<<(E + N + 255) / 256, 256, 0, stream>>>(ei, cursors, offsets, list, E, N);

  // layer 1
  gemm1_att<<<dim3(MBB, 8), 512, 36864, stream>>>(xpk, w1pk, asrc1, adst1, h1b, as1, ad1);
  agg1_gather<<<NITEMS1, 256, 0, stream>>>(h1b, as1, ad1, offsets, list, b1, o1pk, N);

  // layer 2
  gemm2_splitk<<<dim3(Mpad / 64, 4), 256, 16384, stream>>>(o1pk, w2pk, h2p, Mpad);
  reduce_att2<<<(N + 3) / 4, 256, 0, stream>>>(h2p, asrc2, adst2, h2, as2, ad2, Mpad, N);
  agg2_gather<<<NBLK4, 256, 0, stream>>>(h2, as2, ad2, offsets, list, b2, out, N);
}